// Round 1
// baseline (1098.431 us; speedup 1.0000x reference)
//
#include <hip/hip_runtime.h>
#include <hip/hip_bf16.h>

// Problem constants (match reference)
constexpr int R = 3;
constexpr int N = 50000;
constexpr int E = 800000;
constexpr int K = 128;        // IN = HEADS*HID = 128 (both GEMM K dims)
constexpr int COLS1 = 384;    // R * HEADS * HID
constexpr int COLS2 = 192;    // R * HID

// ---------------- CSR build ----------------

__global__ void count_deg(const int* __restrict__ dst, int* __restrict__ deg) {
    int idx = blockIdx.x * blockDim.x + threadIdx.x;
    if (idx >= R * E) return;
    int r = idx / E;
    atomicAdd(&deg[r * N + dst[idx]], 1);
}

// one block per relation; inclusive scan of deg -> rowptr (exclusive form)
__global__ void scan_deg(const int* __restrict__ deg, int* __restrict__ rowptr) {
    const int r = blockIdx.x;
    const int* d = deg + r * N;
    int* rp = rowptr + r * (N + 1);
    __shared__ int buf[1024];
    __shared__ int base_s;
    const int tid = threadIdx.x;
    if (tid == 0) { base_s = 0; rp[0] = 0; }
    __syncthreads();
    for (int chunk = 0; chunk < N; chunk += 1024) {
        int i = chunk + tid;
        int v = (i < N) ? d[i] : 0;
        buf[tid] = v;
        __syncthreads();
        for (int off = 1; off < 1024; off <<= 1) {
            int t = (tid >= off) ? buf[tid - off] : 0;
            __syncthreads();
            buf[tid] += t;
            __syncthreads();
        }
        int incl = buf[tid];
        if (i < N) rp[i + 1] = base_s + incl;
        __syncthreads();
        if (tid == 1023) base_s += incl;
        __syncthreads();
    }
}

__global__ void scatter_edges(const int* __restrict__ src, const int* __restrict__ dst,
                              const int* __restrict__ rowptr, int* __restrict__ cursor,
                              int* __restrict__ srclist) {
    int idx = blockIdx.x * blockDim.x + threadIdx.x;
    if (idx >= R * E) return;
    int r = idx / E;
    int d = dst[idx];
    int pos = rowptr[r * (N + 1) + d] + atomicAdd(&cursor[r * N + d], 1);
    srclist[r * E + pos] = src[idx];
}

// ---------------- GEMM: X[N,128] @ Wcat[128, COLS], W stored [R][128][COLS/R] ----------------

template<int COLS, int JL, int NB>
__global__ __launch_bounds__(COLS) void gemm_rel(const float* __restrict__ X,
                                                 const float* __restrict__ W,
                                                 float* __restrict__ out) {
    __shared__ float xs[NB][K];
    const int n0 = blockIdx.x * NB;
    const int c = threadIdx.x;
    for (int t = c; t < NB * K; t += COLS) {
        xs[t >> 7][t & 127] = X[(n0 + (t >> 7)) * K + (t & 127)];
    }
    __syncthreads();
    const int rr = c >> JL;
    const int j = c & ((1 << JL) - 1);
    const float* wp = W + rr * (K << JL) + j;
    float acc[NB];
#pragma unroll
    for (int b = 0; b < NB; b++) acc[b] = 0.f;
#pragma unroll 8
    for (int k = 0; k < K; k++) {
        float wv = wp[k << JL];
#pragma unroll
        for (int b = 0; b < NB; b++) acc[b] += xs[b][k] * wv;
    }
#pragma unroll
    for (int b = 0; b < NB; b++) out[(n0 + b) * COLS + c] = acc[b];
}

// ---------------- attention logits ----------------

// layer 1: 2 heads. wave per (r,n); el/er stored [R][N][2]
__global__ void attn_l1(const float* __restrict__ feat1, const float* __restrict__ al1,
                        const float* __restrict__ ar1, float* __restrict__ el,
                        float* __restrict__ er) {
    int w = (blockIdx.x * blockDim.x + threadIdx.x) >> 6;
    int lane = threadIdx.x & 63;
    if (w >= N * R) return;
    int r = w / N;
    int n = w - r * N;
    float f0 = feat1[n * COLS1 + r * 128 + lane];
    float f1 = feat1[n * COLS1 + r * 128 + 64 + lane];
    float p00 = f0 * al1[r * 128 + lane];
    float p01 = f0 * ar1[r * 128 + lane];
    float p10 = f1 * al1[r * 128 + 64 + lane];
    float p11 = f1 * ar1[r * 128 + 64 + lane];
#pragma unroll
    for (int off = 32; off; off >>= 1) {
        p00 += __shfl_xor(p00, off);
        p01 += __shfl_xor(p01, off);
        p10 += __shfl_xor(p10, off);
        p11 += __shfl_xor(p11, off);
    }
    if (lane == 0) {
        el[(r * N + n) * 2 + 0] = p00;
        er[(r * N + n) * 2 + 0] = p01;
        el[(r * N + n) * 2 + 1] = p10;
        er[(r * N + n) * 2 + 1] = p11;
    }
}

// layer 2: 1 head. el/er stored [R][N]
__global__ void attn_l2(const float* __restrict__ feat2, const float* __restrict__ al2,
                        const float* __restrict__ ar2, float* __restrict__ el,
                        float* __restrict__ er) {
    int w = (blockIdx.x * blockDim.x + threadIdx.x) >> 6;
    int lane = threadIdx.x & 63;
    if (w >= N * R) return;
    int r = w / N;
    int n = w - r * N;
    float f = feat2[n * COLS2 + r * 64 + lane];
    float pl = f * al2[r * 64 + lane];
    float pr = f * ar2[r * 64 + lane];
#pragma unroll
    for (int off = 32; off; off >>= 1) {
        pl += __shfl_xor(pl, off);
        pr += __shfl_xor(pr, off);
    }
    if (lane == 0) {
        el[r * N + n] = pl;
        er[r * N + n] = pr;
    }
}

// ---------------- aggregation (softmax over incoming edges, weighted sum) ----------------

__device__ inline float lrelu02(float x) { return x > 0.f ? x : 0.2f * x; }
__device__ inline float elu1(float x) { return x > 0.f ? x : expm1f(x); }

// wave per node; lane = dim; loops relations + incoming edges
__global__ void agg_l1(const float* __restrict__ feat1, const float* __restrict__ el,
                       const float* __restrict__ er, const int* __restrict__ rowptr,
                       const int* __restrict__ srclist, const float* __restrict__ b1,
                       float* __restrict__ h1) {
    int n = (blockIdx.x * blockDim.x + threadIdx.x) >> 6;
    int lane = threadIdx.x & 63;
    if (n >= N) return;
    float h0 = 0.f, h1v = 0.f;
    for (int r = 0; r < R; r++) {
        int beg = rowptr[r * (N + 1) + n];
        int end = rowptr[r * (N + 1) + n + 1];
        float er0 = er[(r * N + n) * 2 + 0];
        float er1v = er[(r * N + n) * 2 + 1];
        float acc0 = 0.f, acc1 = 0.f, z0 = 0.f, z1 = 0.f;
        for (int j = beg; j < end; j++) {
            int s = srclist[r * E + j];
            float e0 = __expf(lrelu02(el[(r * N + s) * 2 + 0] + er0));
            float e1 = __expf(lrelu02(el[(r * N + s) * 2 + 1] + er1v));
            z0 += e0;
            z1 += e1;
            const float* fr = feat1 + s * COLS1 + r * 128;
            acc0 += e0 * fr[lane];
            acc1 += e1 * fr[64 + lane];
        }
        float v0 = (end > beg) ? acc0 / z0 : 0.f;
        float v1 = (end > beg) ? acc1 / z1 : 0.f;
        v0 += b1[r * 128 + lane];
        v1 += b1[r * 128 + 64 + lane];
        h0 += elu1(v0);
        h1v += elu1(v1);
    }
    h1[n * 128 + lane] = h0;
    h1[n * 128 + 64 + lane] = h1v;
}

__global__ void agg_l2(const float* __restrict__ feat2, const float* __restrict__ el,
                       const float* __restrict__ er, const int* __restrict__ rowptr,
                       const int* __restrict__ srclist, const float* __restrict__ b2,
                       float* __restrict__ h2) {
    int n = (blockIdx.x * blockDim.x + threadIdx.x) >> 6;
    int lane = threadIdx.x & 63;
    if (n >= N) return;
    float hacc = 0.f;
    for (int r = 0; r < R; r++) {
        int beg = rowptr[r * (N + 1) + n];
        int end = rowptr[r * (N + 1) + n + 1];
        float ern = er[r * N + n];
        float acc = 0.f, z = 0.f;
        for (int j = beg; j < end; j++) {
            int s = srclist[r * E + j];
            float e = __expf(lrelu02(el[r * N + s] + ern));
            z += e;
            acc += e * feat2[s * COLS2 + r * 64 + lane];
        }
        float v = (end > beg) ? acc / z : 0.f;
        v += b2[r * 64 + lane];
        hacc += elu1(v);
    }
    h2[n * 64 + lane] = hacc;
}

// ---------------- final linear: out = h2 @ Wl + bl ----------------

__global__ void final_linear(const float* __restrict__ h2, const float* __restrict__ Wl,
                             const float* __restrict__ bl, float* __restrict__ out) {
    int n = (blockIdx.x * blockDim.x + threadIdx.x) >> 6;
    int lane = threadIdx.x & 63;
    if (n >= N) return;
    float hv = h2[n * 64 + lane];
    float acc = bl[lane];
#pragma unroll
    for (int kk = 0; kk < 64; kk++) {
        float xk = __shfl(hv, kk);
        acc += xk * Wl[kk * 64 + lane];
    }
    out[n * 64 + lane] = acc;
}

// ---------------- launch ----------------

extern "C" void kernel_launch(void* const* d_in, const int* in_sizes, int n_in,
                              void* d_out, int out_size, void* d_ws, size_t ws_size,
                              hipStream_t stream) {
    const float* x   = (const float*)d_in[0];
    const int*   src = (const int*)d_in[1];
    const int*   dst = (const int*)d_in[2];
    const float* W1  = (const float*)d_in[3];
    const float* al1 = (const float*)d_in[4];
    const float* ar1 = (const float*)d_in[5];
    const float* b1  = (const float*)d_in[6];
    const float* W2  = (const float*)d_in[7];
    const float* al2 = (const float*)d_in[8];
    const float* ar2 = (const float*)d_in[9];
    const float* b2  = (const float*)d_in[10];
    const float* Wl  = (const float*)d_in[11];
    const float* bl  = (const float*)d_in[12];
    float* out = (float*)d_out;

    char* ws = (char*)d_ws;
    size_t off = 0;
    auto alloc = [&](size_t bytes) {
        char* p = ws + off;
        off += (bytes + 255) & ~(size_t)255;
        return p;
    };
    float* feat1   = (float*)alloc(sizeof(float) * (size_t)N * COLS1);  // 76.8 MB (reused as feat2)
    float* h1      = (float*)alloc(sizeof(float) * (size_t)N * 128);    // 25.6 MB
    float* h2      = (float*)alloc(sizeof(float) * (size_t)N * 64);     // 12.8 MB
    float* el1     = (float*)alloc(sizeof(float) * (size_t)R * N * 2);
    float* er1     = (float*)alloc(sizeof(float) * (size_t)R * N * 2);
    float* el2     = (float*)alloc(sizeof(float) * (size_t)R * N);
    float* er2     = (float*)alloc(sizeof(float) * (size_t)R * N);
    int*   rowptr  = (int*)alloc(sizeof(int) * (size_t)R * (N + 1));
    int*   deg     = (int*)alloc(sizeof(int) * (size_t)R * N);          // reused as cursor
    int*   srclist = (int*)alloc(sizeof(int) * (size_t)R * E);          // 9.6 MB
    float* feat2 = feat1;  // safe alias: feat1 fully consumed before feat2 is written

    // --- CSR build (shared by both layers) ---
    hipMemsetAsync(deg, 0, sizeof(int) * (size_t)R * N, stream);
    count_deg<<<(R * E + 255) / 256, 256, 0, stream>>>(dst, deg);
    scan_deg<<<R, 1024, 0, stream>>>(deg, rowptr);
    hipMemsetAsync(deg, 0, sizeof(int) * (size_t)R * N, stream);
    scatter_edges<<<(R * E + 255) / 256, 256, 0, stream>>>(src, dst, rowptr, deg, srclist);

    // --- layer 1 ---
    gemm_rel<COLS1, 7, 8><<<N / 8, COLS1, 0, stream>>>(x, W1, feat1);
    attn_l1<<<(N * R * 64 + 255) / 256, 256, 0, stream>>>(feat1, al1, ar1, el1, er1);
    agg_l1<<<(N * 64 + 255) / 256, 256, 0, stream>>>(feat1, el1, er1, rowptr, srclist, b1, h1);

    // --- layer 2 ---
    gemm_rel<COLS2, 6, 8><<<N / 8, COLS2, 0, stream>>>(h1, W2, feat2);
    attn_l2<<<(N * R * 64 + 255) / 256, 256, 0, stream>>>(feat2, al2, ar2, el2, er2);
    agg_l2<<<(N * 64 + 255) / 256, 256, 0, stream>>>(feat2, el2, er2, rowptr, srclist, b2, h2);

    // --- final linear ---
    final_linear<<<(N * 64 + 255) / 256, 256, 0, stream>>>(h2, Wl, bl, out);
}

// Round 2
// 908.794 us; speedup vs baseline: 1.2087x; 1.2087x over previous
//
#include <hip/hip_runtime.h>

constexpr int R = 3;
constexpr int N = 50000;
constexpr int E = 800000;
constexpr int K = 128;        // IN = HEADS*HID = 128 (both GEMM K dims)
constexpr int COLS1 = 384;    // R * HEADS * HID
constexpr int COLS2 = 192;    // R * HID

// ---------------- bf16 helpers (RNE) ----------------

__device__ inline unsigned short f2bf(float f) {
    unsigned u = __float_as_uint(f);
    u += 0x7FFF + ((u >> 16) & 1);
    return (unsigned short)(u >> 16);
}
__device__ inline float bf2f_lo(unsigned p) { return __uint_as_float(p << 16); }
__device__ inline float bf2f_hi(unsigned p) { return __uint_as_float(p & 0xFFFF0000u); }
__device__ inline float bf2f(unsigned short b) { return __uint_as_float(((unsigned)b) << 16); }

__device__ inline float lrelu02(float x) { return x > 0.f ? x : 0.2f * x; }
__device__ inline float elu1(float x) { return x > 0.f ? x : expm1f(x); }

// ---------------- CSR build ----------------

__global__ void count_deg(const int* __restrict__ dst, int* __restrict__ deg) {
    int idx = blockIdx.x * blockDim.x + threadIdx.x;
    if (idx >= R * E) return;
    int r = idx / E;
    atomicAdd(&deg[r * N + dst[idx]], 1);
}

// one block per relation; wave-shuffle scan, 4 barriers per 1024-chunk
__global__ __launch_bounds__(1024) void scan_deg(const int* __restrict__ deg,
                                                 int* __restrict__ rowptr) {
    const int r = blockIdx.x;
    const int* d = deg + r * N;
    int* rp = rowptr + r * (N + 1);
    __shared__ int wsum[16];
    __shared__ int carry;
    const int tid = threadIdx.x;
    const int lane = tid & 63;
    const int w = tid >> 6;
    if (tid == 0) { carry = 0; rp[0] = 0; }
    __syncthreads();
    for (int chunk = 0; chunk < N; chunk += 1024) {
        int i = chunk + tid;
        int x = (i < N) ? d[i] : 0;
#pragma unroll
        for (int off = 1; off < 64; off <<= 1) {
            int t = __shfl_up(x, off);
            if (lane >= off) x += t;
        }
        if (lane == 63) wsum[w] = x;
        __syncthreads();
        if (w == 0 && lane < 16) {
            int y = wsum[lane];
#pragma unroll
            for (int off = 1; off < 16; off <<= 1) {
                int t = __shfl_up(y, off);
                if (lane >= off) y += t;
            }
            wsum[lane] = y;
        }
        __syncthreads();
        int add = carry + (w > 0 ? wsum[w - 1] : 0);
        if (i < N) rp[i + 1] = add + x;
        __syncthreads();
        if (tid == 0) carry += wsum[15];
        __syncthreads();
    }
}

__global__ void scatter_edges(const int* __restrict__ src, const int* __restrict__ dst,
                              const int* __restrict__ rowptr, int* __restrict__ cursor,
                              int* __restrict__ srclist) {
    int idx = blockIdx.x * blockDim.x + threadIdx.x;
    if (idx >= R * E) return;
    int r = idx / E;
    int d = dst[idx];
    int pos = rowptr[r * (N + 1) + d] + atomicAdd(&cursor[r * N + d], 1);
    srclist[r * E + pos] = src[idx];
}

// ---------------- GEMM1: X[N,128] @ W1[R][128][128] -> packed bf16x2 (head0|head1) ----------------

__global__ __launch_bounds__(COLS1) void gemm1_pack(const float* __restrict__ X,
                                                    const float* __restrict__ W,
                                                    unsigned* __restrict__ packed1) {
    __shared__ float sm[8 * COLS1];        // epilogue staging; first 1024 floats double as xs
    float* xs = sm;                        // xs[b*128 + k]
    const int n0 = blockIdx.x * 8;
    const int c = threadIdx.x;
    for (int t = c; t < 8 * K; t += COLS1)
        xs[t] = X[(size_t)(n0 + (t >> 7)) * K + (t & 127)];
    __syncthreads();
    const int rr = c >> 7;                 // relation
    const int j = c & 127;                 // column within relation
    const float* wp = W + (size_t)rr * (K * 128) + j;
    float acc[8];
#pragma unroll
    for (int b = 0; b < 8; b++) acc[b] = 0.f;
#pragma unroll 8
    for (int k = 0; k < K; k++) {
        float wv = wp[(size_t)k * 128];
#pragma unroll
        for (int b = 0; b < 8; b++) acc[b] += xs[b * 128 + k] * wv;
    }
    __syncthreads();                       // xs reads done; reuse sm
#pragma unroll
    for (int b = 0; b < 8; b++) sm[b * COLS1 + c] = acc[b];
    __syncthreads();
    if (c < 192) {
        int r = c >> 6, d = c & 63;
#pragma unroll
        for (int b = 0; b < 8; b++) {
            float f0 = sm[b * COLS1 + r * 128 + d];
            float f1 = sm[b * COLS1 + r * 128 + 64 + d];
            packed1[((size_t)(n0 + b) * R + r) * 64 + d] =
                (unsigned)f2bf(f0) | ((unsigned)f2bf(f1) << 16);
        }
    }
}

// ---------------- GEMM2: h1[N,128] @ W2[R][128][64] -> packed bf16 ushort ----------------

__global__ __launch_bounds__(COLS2) void gemm2_pack(const float* __restrict__ X,
                                                    const float* __restrict__ W,
                                                    unsigned short* __restrict__ packed2) {
    __shared__ float xs[8 * K];
    const int n0 = blockIdx.x * 8;
    const int c = threadIdx.x;
    for (int t = c; t < 8 * K; t += COLS2)
        xs[t] = X[(size_t)(n0 + (t >> 7)) * K + (t & 127)];
    __syncthreads();
    const int rr = c >> 6;
    const int j = c & 63;
    const float* wp = W + (size_t)rr * (K * 64) + j;
    float acc[8];
#pragma unroll
    for (int b = 0; b < 8; b++) acc[b] = 0.f;
#pragma unroll 8
    for (int k = 0; k < K; k++) {
        float wv = wp[(size_t)k * 64];
#pragma unroll
        for (int b = 0; b < 8; b++) acc[b] += xs[b * 128 + k] * wv;
    }
#pragma unroll
    for (int b = 0; b < 8; b++)
        packed2[((size_t)(n0 + b) * R + rr) * 64 + j] = f2bf(acc[b]);
}

// ---------------- attention logits ----------------

// layer 1: el/er stored as float2-compatible [(r*N+n)*2 + head]
__global__ void attn_l1(const unsigned* __restrict__ packed1, const float* __restrict__ al1,
                        const float* __restrict__ ar1, float* __restrict__ el,
                        float* __restrict__ er) {
    int w = (blockIdx.x * blockDim.x + threadIdx.x) >> 6;
    int lane = threadIdx.x & 63;
    if (w >= N * R) return;
    int r = w / N;
    int n = w - r * N;
    unsigned p = packed1[((size_t)n * R + r) * 64 + lane];
    float f0 = bf2f_lo(p), f1 = bf2f_hi(p);
    float p00 = f0 * al1[r * 128 + lane];
    float p01 = f0 * ar1[r * 128 + lane];
    float p10 = f1 * al1[r * 128 + 64 + lane];
    float p11 = f1 * ar1[r * 128 + 64 + lane];
#pragma unroll
    for (int off = 32; off; off >>= 1) {
        p00 += __shfl_xor(p00, off);
        p01 += __shfl_xor(p01, off);
        p10 += __shfl_xor(p10, off);
        p11 += __shfl_xor(p11, off);
    }
    if (lane == 0) {
        el[(r * N + n) * 2 + 0] = p00;
        el[(r * N + n) * 2 + 1] = p10;
        er[(r * N + n) * 2 + 0] = p01;
        er[(r * N + n) * 2 + 1] = p11;
    }
}

// layer 2: el/er stored [r*N+n]
__global__ void attn_l2(const unsigned short* __restrict__ packed2, const float* __restrict__ al2,
                        const float* __restrict__ ar2, float* __restrict__ el,
                        float* __restrict__ er) {
    int w = (blockIdx.x * blockDim.x + threadIdx.x) >> 6;
    int lane = threadIdx.x & 63;
    if (w >= N * R) return;
    int r = w / N;
    int n = w - r * N;
    float f = bf2f(packed2[((size_t)n * R + r) * 64 + lane]);
    float pl = f * al2[r * 64 + lane];
    float pr = f * ar2[r * 64 + lane];
#pragma unroll
    for (int off = 32; off; off >>= 1) {
        pl += __shfl_xor(pl, off);
        pr += __shfl_xor(pr, off);
    }
    if (lane == 0) {
        el[r * N + n] = pl;
        er[r * N + n] = pr;
    }
}

// ---------------- aggregation ----------------

__global__ void agg_l1(const unsigned* __restrict__ packed1, const float* __restrict__ el,
                       const float* __restrict__ er, const int* __restrict__ rowptr,
                       const int* __restrict__ srclist, const float* __restrict__ b1,
                       float* __restrict__ h1) {
    int n = (blockIdx.x * blockDim.x + threadIdx.x) >> 6;
    int lane = threadIdx.x & 63;
    if (n >= N) return;
    const float2* el2 = (const float2*)el;
    float h0 = 0.f, h1v = 0.f;
    for (int r = 0; r < R; r++) {
        int beg = rowptr[r * (N + 1) + n];
        int end = rowptr[r * (N + 1) + n + 1];
        float2 erp = ((const float2*)er)[r * N + n];
        const int* sl = srclist + r * E;
        const int rbase = r * N;
        float acc0 = 0.f, acc1 = 0.f, z0 = 0.f, z1 = 0.f;
        int j = beg;
        for (; j + 1 < end; j += 2) {
            int s0 = sl[j], s1 = sl[j + 1];
            float2 ea = el2[rbase + s0];
            float2 eb = el2[rbase + s1];
            unsigned pa = packed1[((size_t)s0 * R + r) * 64 + lane];
            unsigned pb = packed1[((size_t)s1 * R + r) * 64 + lane];
            float w00 = __expf(lrelu02(ea.x + erp.x));
            float w01 = __expf(lrelu02(ea.y + erp.y));
            float w10 = __expf(lrelu02(eb.x + erp.x));
            float w11 = __expf(lrelu02(eb.y + erp.y));
            z0 += w00 + w10;
            z1 += w01 + w11;
            acc0 += w00 * bf2f_lo(pa) + w10 * bf2f_lo(pb);
            acc1 += w01 * bf2f_hi(pa) + w11 * bf2f_hi(pb);
        }
        if (j < end) {
            int s0 = sl[j];
            float2 ea = el2[rbase + s0];
            unsigned pa = packed1[((size_t)s0 * R + r) * 64 + lane];
            float w00 = __expf(lrelu02(ea.x + erp.x));
            float w01 = __expf(lrelu02(ea.y + erp.y));
            z0 += w00;
            z1 += w01;
            acc0 += w00 * bf2f_lo(pa);
            acc1 += w01 * bf2f_hi(pa);
        }
        float v0 = (end > beg) ? acc0 / z0 : 0.f;
        float v1 = (end > beg) ? acc1 / z1 : 0.f;
        v0 += b1[r * 128 + lane];
        v1 += b1[r * 128 + 64 + lane];
        h0 += elu1(v0);
        h1v += elu1(v1);
    }
    h1[(size_t)n * 128 + lane] = h0;
    h1[(size_t)n * 128 + 64 + lane] = h1v;
}

__global__ void agg_l2(const unsigned short* __restrict__ packed2, const float* __restrict__ el,
                       const float* __restrict__ er, const int* __restrict__ rowptr,
                       const int* __restrict__ srclist, const float* __restrict__ b2,
                       float* __restrict__ h2) {
    int n = (blockIdx.x * blockDim.x + threadIdx.x) >> 6;
    int lane = threadIdx.x & 63;
    if (n >= N) return;
    float hacc = 0.f;
    for (int r = 0; r < R; r++) {
        int beg = rowptr[r * (N + 1) + n];
        int end = rowptr[r * (N + 1) + n + 1];
        float ern = er[r * N + n];
        const int* sl = srclist + r * E;
        const int rbase = r * N;
        float acc = 0.f, z = 0.f;
        int j = beg;
        for (; j + 1 < end; j += 2) {
            int s0 = sl[j], s1 = sl[j + 1];
            float ea = el[rbase + s0];
            float eb = el[rbase + s1];
            float fa = bf2f(packed2[((size_t)s0 * R + r) * 64 + lane]);
            float fb = bf2f(packed2[((size_t)s1 * R + r) * 64 + lane]);
            float wa = __expf(lrelu02(ea + ern));
            float wb = __expf(lrelu02(eb + ern));
            z += wa + wb;
            acc += wa * fa + wb * fb;
        }
        if (j < end) {
            int s0 = sl[j];
            float ea = el[rbase + s0];
            float fa = bf2f(packed2[((size_t)s0 * R + r) * 64 + lane]);
            float wa = __expf(lrelu02(ea + ern));
            z += wa;
            acc += wa * fa;
        }
        float v = (end > beg) ? acc / z : 0.f;
        v += b2[r * 64 + lane];
        hacc += elu1(v);
    }
    h2[(size_t)n * 64 + lane] = hacc;
}

// ---------------- final linear: out = h2 @ Wl + bl ----------------

__global__ void final_linear(const float* __restrict__ h2, const float* __restrict__ Wl,
                             const float* __restrict__ bl, float* __restrict__ out) {
    int n = (blockIdx.x * blockDim.x + threadIdx.x) >> 6;
    int lane = threadIdx.x & 63;
    if (n >= N) return;
    float hv = h2[(size_t)n * 64 + lane];
    float acc = bl[lane];
#pragma unroll
    for (int kk = 0; kk < 64; kk++) {
        float xk = __shfl(hv, kk);
        acc += xk * Wl[kk * 64 + lane];
    }
    out[(size_t)n * 64 + lane] = acc;
}

// ---------------- launch ----------------

extern "C" void kernel_launch(void* const* d_in, const int* in_sizes, int n_in,
                              void* d_out, int out_size, void* d_ws, size_t ws_size,
                              hipStream_t stream) {
    const float* x   = (const float*)d_in[0];
    const int*   src = (const int*)d_in[1];
    const int*   dst = (const int*)d_in[2];
    const float* W1  = (const float*)d_in[3];
    const float* al1 = (const float*)d_in[4];
    const float* ar1 = (const float*)d_in[5];
    const float* b1  = (const float*)d_in[6];
    const float* W2  = (const float*)d_in[7];
    const float* al2 = (const float*)d_in[8];
    const float* ar2 = (const float*)d_in[9];
    const float* b2  = (const float*)d_in[10];
    const float* Wl  = (const float*)d_in[11];
    const float* bl  = (const float*)d_in[12];
    float* out = (float*)d_out;

    char* ws = (char*)d_ws;
    size_t off = 0;
    auto alloc = [&](size_t bytes) {
        char* p = ws + off;
        off += (bytes + 255) & ~(size_t)255;
        return p;
    };
    unsigned*       packed1 = (unsigned*)alloc(sizeof(unsigned) * (size_t)N * R * 64);        // 38.4 MB
    unsigned short* packed2 = (unsigned short*)alloc(sizeof(unsigned short) * (size_t)N * R * 64); // 19.2 MB
    float* h1      = (float*)alloc(sizeof(float) * (size_t)N * 128);    // 25.6 MB
    float* h2      = (float*)alloc(sizeof(float) * (size_t)N * 64);     // 12.8 MB
    float* el1     = (float*)alloc(sizeof(float) * (size_t)R * N * 2);
    float* er1     = (float*)alloc(sizeof(float) * (size_t)R * N * 2);
    float* el2     = (float*)alloc(sizeof(float) * (size_t)R * N);
    float* er2     = (float*)alloc(sizeof(float) * (size_t)R * N);
    int*   rowptr  = (int*)alloc(sizeof(int) * (size_t)R * (N + 1));
    int*   deg     = (int*)alloc(sizeof(int) * (size_t)R * N);          // reused as cursor
    int*   srclist = (int*)alloc(sizeof(int) * (size_t)R * E);          // 9.6 MB

    // --- CSR build (shared by both layers) ---
    hipMemsetAsync(deg, 0, sizeof(int) * (size_t)R * N, stream);
    count_deg<<<(R * E + 255) / 256, 256, 0, stream>>>(dst, deg);
    scan_deg<<<R, 1024, 0, stream>>>(deg, rowptr);
    hipMemsetAsync(deg, 0, sizeof(int) * (size_t)R * N, stream);
    scatter_edges<<<(R * E + 255) / 256, 256, 0, stream>>>(src, dst, rowptr, deg, srclist);

    // --- layer 1 ---
    gemm1_pack<<<N / 8, COLS1, 0, stream>>>(x, W1, packed1);
    attn_l1<<<(N * R * 64 + 255) / 256, 256, 0, stream>>>(packed1, al1, ar1, el1, er1);
    agg_l1<<<(N * 64 + 255) / 256, 256, 0, stream>>>(packed1, el1, er1, rowptr, srclist, b1, h1);

    // --- layer 2 ---
    gemm2_pack<<<N / 8, COLS2, 0, stream>>>(h1, W2, packed2);
    attn_l2<<<(N * R * 64 + 255) / 256, 256, 0, stream>>>(packed2, al2, ar2, el2, er2);
    agg_l2<<<(N * 64 + 255) / 256, 256, 0, stream>>>(packed2, el2, er2, rowptr, srclist, b2, h2);

    // --- final linear ---
    final_linear<<<(N * 64 + 255) / 256, 256, 0, stream>>>(h2, Wl, bl, out);
}

// Round 3
// 860.278 us; speedup vs baseline: 1.2768x; 1.0564x over previous
//
#include <hip/hip_runtime.h>

constexpr int R = 3;
constexpr int N = 50000;
constexpr int E = 800000;
constexpr int K = 128;        // IN = HEADS*HID = 128 (both GEMM K dims)
constexpr int COLS1 = 384;    // R * HEADS * HID
constexpr int COLS2 = 192;    // R * HID
constexpr int NB = (N + 1023) / 1024;  // scan blocks per relation = 49

// ---------------- bf16 helpers (RNE) ----------------

__device__ inline unsigned short f2bf(float f) {
    unsigned u = __float_as_uint(f);
    u += 0x7FFF + ((u >> 16) & 1);
    return (unsigned short)(u >> 16);
}
__device__ inline float bf2f_lo(unsigned p) { return __uint_as_float(p << 16); }
__device__ inline float bf2f_hi(unsigned p) { return __uint_as_float(p & 0xFFFF0000u); }
__device__ inline float bf2f(unsigned short b) { return __uint_as_float(((unsigned)b) << 16); }

__device__ inline float lrelu02(float x) { return x > 0.f ? x : 0.2f * x; }
__device__ inline float elu1(float x) { return x > 0.f ? x : expm1f(x); }

// ---------------- CSR build ----------------

__global__ void count_deg(const int* __restrict__ dst, int* __restrict__ deg) {
    int idx = blockIdx.x * blockDim.x + threadIdx.x;
    if (idx >= R * E) return;
    int r = idx / E;
    atomicAdd(&deg[r * N + dst[idx]], 1);
}

// phase A: per-1024-block local inclusive scan; write into rowptr[+1], block sums to bsum
__global__ __launch_bounds__(1024) void scanA(const int* __restrict__ deg,
                                              int* __restrict__ rowptr,
                                              int* __restrict__ bsum) {
    const int r = blockIdx.y;
    const int b = blockIdx.x;
    const int tid = threadIdx.x;
    const int lane = tid & 63;
    const int w = tid >> 6;
    const int i = b * 1024 + tid;
    int x = (i < N) ? deg[r * N + i] : 0;
#pragma unroll
    for (int off = 1; off < 64; off <<= 1) {
        int t = __shfl_up(x, off);
        if (lane >= off) x += t;
    }
    __shared__ int wsum[16];
    if (lane == 63) wsum[w] = x;
    __syncthreads();
    if (tid < 16) {
        int y = wsum[tid];
#pragma unroll
        for (int off = 1; off < 16; off <<= 1) {
            int t = __shfl_up(y, off);
            if (tid >= off) y += t;
        }
        wsum[tid] = y;
    }
    __syncthreads();
    int incl = x + (w > 0 ? wsum[w - 1] : 0);
    if (i < N) rowptr[r * (N + 1) + i + 1] = incl;
    if (tid == 1023) bsum[r * NB + b] = incl;
}

// phase B: scan block sums (one wave per relation)
__global__ void scanB(const int* __restrict__ bsum, int* __restrict__ boff) {
    int w = threadIdx.x >> 6, lane = threadIdx.x & 63;
    if (w >= R) return;
    int v = (lane < NB) ? bsum[w * NB + lane] : 0;
    int incl = v;
#pragma unroll
    for (int off = 1; off < 64; off <<= 1) {
        int t = __shfl_up(incl, off);
        if (lane >= off) incl += t;
    }
    if (lane < NB) boff[w * NB + lane] = incl - v;  // exclusive
}

// phase C: add block offsets
__global__ __launch_bounds__(1024) void scanC(int* __restrict__ rowptr,
                                              const int* __restrict__ boff) {
    const int r = blockIdx.y;
    const int b = blockIdx.x;
    const int i = b * 1024 + threadIdx.x;
    if (i < N) rowptr[r * (N + 1) + i + 1] += boff[r * NB + b];
    if (i == 0) rowptr[r * (N + 1)] = 0;
}

__global__ void scatter_edges(const int* __restrict__ src, const int* __restrict__ dst,
                              const int* __restrict__ rowptr, int* __restrict__ cursor,
                              int* __restrict__ srclist) {
    int idx = blockIdx.x * blockDim.x + threadIdx.x;
    if (idx >= R * E) return;
    int r = idx / E;
    int d = dst[idx];
    int pos = rowptr[r * (N + 1) + d] + atomicAdd(&cursor[r * N + d], 1);
    srclist[r * E + pos] = src[idx];
}

// ---------------- GEMM1: X[N,128] @ W1[R][128][128] -> packed bf16x2 (head0|head1) ----------------

__global__ __launch_bounds__(COLS1) void gemm1_pack(const float* __restrict__ X,
                                                    const float* __restrict__ W,
                                                    unsigned* __restrict__ packed1) {
    __shared__ float sm[8 * COLS1];        // epilogue staging; first 1024 floats double as xs
    float* xs = sm;
    const int n0 = blockIdx.x * 8;
    const int c = threadIdx.x;
    for (int t = c; t < 8 * K; t += COLS1)
        xs[t] = X[(size_t)(n0 + (t >> 7)) * K + (t & 127)];
    __syncthreads();
    const int rr = c >> 7;
    const int j = c & 127;
    const float* wp = W + (size_t)rr * (K * 128) + j;
    float acc[8];
#pragma unroll
    for (int b = 0; b < 8; b++) acc[b] = 0.f;
#pragma unroll 8
    for (int k = 0; k < K; k++) {
        float wv = wp[(size_t)k * 128];
#pragma unroll
        for (int b = 0; b < 8; b++) acc[b] += xs[b * 128 + k] * wv;
    }
    __syncthreads();
#pragma unroll
    for (int b = 0; b < 8; b++) sm[b * COLS1 + c] = acc[b];
    __syncthreads();
    if (c < 192) {
        int r = c >> 6, d = c & 63;
#pragma unroll
        for (int b = 0; b < 8; b++) {
            float f0 = sm[b * COLS1 + r * 128 + d];
            float f1 = sm[b * COLS1 + r * 128 + 64 + d];
            packed1[((size_t)(n0 + b) * R + r) * 64 + d] =
                (unsigned)f2bf(f0) | ((unsigned)f2bf(f1) << 16);
        }
    }
}

// ---------------- GEMM2: h1[N,128] @ W2[R][128][64] -> packed bf16 ushort ----------------

__global__ __launch_bounds__(COLS2) void gemm2_pack(const float* __restrict__ X,
                                                    const float* __restrict__ W,
                                                    unsigned short* __restrict__ packed2) {
    __shared__ float xs[8 * K];
    const int n0 = blockIdx.x * 8;
    const int c = threadIdx.x;
    for (int t = c; t < 8 * K; t += COLS2)
        xs[t] = X[(size_t)(n0 + (t >> 7)) * K + (t & 127)];
    __syncthreads();
    const int rr = c >> 6;
    const int j = c & 63;
    const float* wp = W + (size_t)rr * (K * 64) + j;
    float acc[8];
#pragma unroll
    for (int b = 0; b < 8; b++) acc[b] = 0.f;
#pragma unroll 8
    for (int k = 0; k < K; k++) {
        float wv = wp[(size_t)k * 64];
#pragma unroll
        for (int b = 0; b < 8; b++) acc[b] += xs[b * 128 + k] * wv;
    }
#pragma unroll
    for (int b = 0; b < 8; b++)
        packed2[((size_t)(n0 + b) * R + rr) * 64 + j] = f2bf(acc[b]);
}

// ---------------- attention logits ----------------

__global__ void attn_l1(const unsigned* __restrict__ packed1, const float* __restrict__ al1,
                        const float* __restrict__ ar1, float* __restrict__ el,
                        float* __restrict__ er) {
    int w = (blockIdx.x * blockDim.x + threadIdx.x) >> 6;
    int lane = threadIdx.x & 63;
    if (w >= N * R) return;
    int r = w / N;
    int n = w - r * N;
    unsigned p = packed1[((size_t)n * R + r) * 64 + lane];
    float f0 = bf2f_lo(p), f1 = bf2f_hi(p);
    float p00 = f0 * al1[r * 128 + lane];
    float p01 = f0 * ar1[r * 128 + lane];
    float p10 = f1 * al1[r * 128 + 64 + lane];
    float p11 = f1 * ar1[r * 128 + 64 + lane];
#pragma unroll
    for (int off = 32; off; off >>= 1) {
        p00 += __shfl_xor(p00, off);
        p01 += __shfl_xor(p01, off);
        p10 += __shfl_xor(p10, off);
        p11 += __shfl_xor(p11, off);
    }
    if (lane == 0) {
        el[(r * N + n) * 2 + 0] = p00;
        el[(r * N + n) * 2 + 1] = p10;
        er[(r * N + n) * 2 + 0] = p01;
        er[(r * N + n) * 2 + 1] = p11;
    }
}

__global__ void attn_l2(const unsigned short* __restrict__ packed2, const float* __restrict__ al2,
                        const float* __restrict__ ar2, float* __restrict__ el,
                        float* __restrict__ er) {
    int w = (blockIdx.x * blockDim.x + threadIdx.x) >> 6;
    int lane = threadIdx.x & 63;
    if (w >= N * R) return;
    int r = w / N;
    int n = w - r * N;
    float f = bf2f(packed2[((size_t)n * R + r) * 64 + lane]);
    float pl = f * al2[r * 64 + lane];
    float pr = f * ar2[r * 64 + lane];
#pragma unroll
    for (int off = 32; off; off >>= 1) {
        pl += __shfl_xor(pl, off);
        pr += __shfl_xor(pr, off);
    }
    if (lane == 0) {
        el[r * N + n] = pl;
        er[r * N + n] = pr;
    }
}

// ---------------- normalized edge weights (CSR order), 16-lane group per node ----------------

__global__ void edge_w1(const float* __restrict__ el_, const float* __restrict__ er_,
                        const int* __restrict__ rowptr, const int* __restrict__ srclist,
                        float2* __restrict__ aw) {
    int wid = (blockIdx.x * blockDim.x + threadIdx.x) >> 6;
    int lane = threadIdx.x & 63;
    int g = lane >> 4, li = lane & 15;
    int node = wid * 4 + g;
    if (node >= R * N) return;
    int r = node / N, n = node - r * N;
    const float2* el2 = (const float2*)el_;
    float2 ern = ((const float2*)er_)[r * N + n];
    int beg = rowptr[r * (N + 1) + n], end = rowptr[r * (N + 1) + n + 1];
    const int* sl = srclist + r * E;
    float z0 = 0.f, z1 = 0.f;
    for (int j = beg + li; j < end; j += 16) {
        float2 e = el2[r * N + sl[j]];
        z0 += __expf(lrelu02(e.x + ern.x));
        z1 += __expf(lrelu02(e.y + ern.y));
    }
#pragma unroll
    for (int off = 1; off < 16; off <<= 1) {
        z0 += __shfl_xor(z0, off);
        z1 += __shfl_xor(z1, off);
    }
    float rz0 = (end > beg) ? 1.0f / z0 : 0.f;
    float rz1 = (end > beg) ? 1.0f / z1 : 0.f;
    for (int j = beg + li; j < end; j += 16) {
        float2 e = el2[r * N + sl[j]];
        aw[(size_t)r * E + j] = make_float2(__expf(lrelu02(e.x + ern.x)) * rz0,
                                            __expf(lrelu02(e.y + ern.y)) * rz1);
    }
}

__global__ void edge_w2(const float* __restrict__ el, const float* __restrict__ er,
                        const int* __restrict__ rowptr, const int* __restrict__ srclist,
                        float* __restrict__ aw) {
    int wid = (blockIdx.x * blockDim.x + threadIdx.x) >> 6;
    int lane = threadIdx.x & 63;
    int g = lane >> 4, li = lane & 15;
    int node = wid * 4 + g;
    if (node >= R * N) return;
    int r = node / N, n = node - r * N;
    float ern = er[r * N + n];
    int beg = rowptr[r * (N + 1) + n], end = rowptr[r * (N + 1) + n + 1];
    const int* sl = srclist + r * E;
    float z = 0.f;
    for (int j = beg + li; j < end; j += 16) {
        z += __expf(lrelu02(el[r * N + sl[j]] + ern));
    }
#pragma unroll
    for (int off = 1; off < 16; off <<= 1) z += __shfl_xor(z, off);
    float rz = (end > beg) ? 1.0f / z : 0.f;
    for (int j = beg + li; j < end; j += 16) {
        aw[(size_t)r * E + j] = __expf(lrelu02(el[r * N + sl[j]] + ern)) * rz;
    }
}

// ---------------- aggregation: pure weighted gathers ----------------

__global__ void agg_l1(const unsigned* __restrict__ packed1, const float2* __restrict__ aw1,
                       const int* __restrict__ rowptr, const int* __restrict__ srclist,
                       const float* __restrict__ b1, float* __restrict__ h1) {
    int n = (blockIdx.x * blockDim.x + threadIdx.x) >> 6;
    int lane = threadIdx.x & 63;
    if (n >= N) return;
    float h0 = 0.f, h1v = 0.f;
    for (int r = 0; r < R; r++) {
        int beg = rowptr[r * (N + 1) + n];
        int end = rowptr[r * (N + 1) + n + 1];
        const int* sl = srclist + r * E;
        const float2* awr = aw1 + (size_t)r * E;
        float acc0 = 0.f, acc1 = 0.f;
        int j = beg;
        for (; j + 1 < end; j += 2) {
            int s0 = __builtin_amdgcn_readfirstlane(sl[j]);
            int s1 = __builtin_amdgcn_readfirstlane(sl[j + 1]);
            float2 a0 = awr[j];
            float2 a1 = awr[j + 1];
            unsigned pa = packed1[((size_t)s0 * R + r) * 64 + lane];
            unsigned pb = packed1[((size_t)s1 * R + r) * 64 + lane];
            acc0 += a0.x * bf2f_lo(pa) + a1.x * bf2f_lo(pb);
            acc1 += a0.y * bf2f_hi(pa) + a1.y * bf2f_hi(pb);
        }
        if (j < end) {
            int s0 = __builtin_amdgcn_readfirstlane(sl[j]);
            float2 a0 = awr[j];
            unsigned pa = packed1[((size_t)s0 * R + r) * 64 + lane];
            acc0 += a0.x * bf2f_lo(pa);
            acc1 += a0.y * bf2f_hi(pa);
        }
        h0 += elu1(acc0 + b1[r * 128 + lane]);
        h1v += elu1(acc1 + b1[r * 128 + 64 + lane]);
    }
    h1[(size_t)n * 128 + lane] = h0;
    h1[(size_t)n * 128 + 64 + lane] = h1v;
}

// agg layer2 fused with final linear (Wl staged in LDS)
__global__ __launch_bounds__(256) void agg_l2_final(const unsigned short* __restrict__ packed2,
                                                    const float* __restrict__ aw2,
                                                    const int* __restrict__ rowptr,
                                                    const int* __restrict__ srclist,
                                                    const float* __restrict__ b2,
                                                    const float* __restrict__ Wl,
                                                    const float* __restrict__ bl,
                                                    float* __restrict__ out) {
    __shared__ float wl_s[64 * 64];
    for (int t = threadIdx.x; t < 64 * 64; t += 256) wl_s[t] = Wl[t];
    __syncthreads();
    int n = (blockIdx.x * blockDim.x + threadIdx.x) >> 6;
    int lane = threadIdx.x & 63;
    if (n >= N) return;
    float hacc = 0.f;
    for (int r = 0; r < R; r++) {
        int beg = rowptr[r * (N + 1) + n];
        int end = rowptr[r * (N + 1) + n + 1];
        const int* sl = srclist + r * E;
        const float* awr = aw2 + (size_t)r * E;
        float acc = 0.f;
        int j = beg;
        for (; j + 1 < end; j += 2) {
            int s0 = __builtin_amdgcn_readfirstlane(sl[j]);
            int s1 = __builtin_amdgcn_readfirstlane(sl[j + 1]);
            float a0 = awr[j];
            float a1 = awr[j + 1];
            float fa = bf2f(packed2[((size_t)s0 * R + r) * 64 + lane]);
            float fb = bf2f(packed2[((size_t)s1 * R + r) * 64 + lane]);
            acc += a0 * fa + a1 * fb;
        }
        if (j < end) {
            int s0 = __builtin_amdgcn_readfirstlane(sl[j]);
            acc += awr[j] * bf2f(packed2[((size_t)s0 * R + r) * 64 + lane]);
        }
        hacc += elu1(acc + b2[r * 64 + lane]);
    }
    float res = bl[lane];
#pragma unroll
    for (int kk = 0; kk < 64; kk++) {
        float xk = __shfl(hacc, kk);
        res += xk * wl_s[kk * 64 + lane];
    }
    out[(size_t)n * 64 + lane] = res;
}

// ---------------- launch ----------------

extern "C" void kernel_launch(void* const* d_in, const int* in_sizes, int n_in,
                              void* d_out, int out_size, void* d_ws, size_t ws_size,
                              hipStream_t stream) {
    const float* x   = (const float*)d_in[0];
    const int*   src = (const int*)d_in[1];
    const int*   dst = (const int*)d_in[2];
    const float* W1  = (const float*)d_in[3];
    const float* al1 = (const float*)d_in[4];
    const float* ar1 = (const float*)d_in[5];
    const float* b1  = (const float*)d_in[6];
    const float* W2  = (const float*)d_in[7];
    const float* al2 = (const float*)d_in[8];
    const float* ar2 = (const float*)d_in[9];
    const float* b2  = (const float*)d_in[10];
    const float* Wl  = (const float*)d_in[11];
    const float* bl  = (const float*)d_in[12];
    float* out = (float*)d_out;

    char* ws = (char*)d_ws;
    size_t off = 0;
    auto alloc = [&](size_t bytes) {
        char* p = ws + off;
        off += (bytes + 255) & ~(size_t)255;
        return p;
    };
    unsigned*       packed1 = (unsigned*)alloc(sizeof(unsigned) * (size_t)N * R * 64);        // 38.4 MB
    unsigned short* packed2 = (unsigned short*)alloc(sizeof(unsigned short) * (size_t)N * R * 64); // 19.2 MB
    float* h1      = (float*)alloc(sizeof(float) * (size_t)N * 128);    // 25.6 MB
    float2* aw1    = (float2*)alloc(sizeof(float2) * (size_t)R * E);    // 19.2 MB
    float* aw2     = (float*)alloc(sizeof(float) * (size_t)R * E);      // 9.6 MB
    float* el1     = (float*)alloc(sizeof(float) * (size_t)R * N * 2);
    float* er1     = (float*)alloc(sizeof(float) * (size_t)R * N * 2);
    float* el2     = (float*)alloc(sizeof(float) * (size_t)R * N);
    float* er2     = (float*)alloc(sizeof(float) * (size_t)R * N);
    int*   rowptr  = (int*)alloc(sizeof(int) * (size_t)R * (N + 1));
    int*   deg     = (int*)alloc(sizeof(int) * (size_t)R * N);          // reused as cursor
    int*   srclist = (int*)alloc(sizeof(int) * (size_t)R * E);          // 9.6 MB
    int*   bsum    = (int*)alloc(sizeof(int) * (size_t)R * NB);
    int*   boff    = (int*)alloc(sizeof(int) * (size_t)R * NB);

    // --- CSR build (shared by both layers) ---
    hipMemsetAsync(deg, 0, sizeof(int) * (size_t)R * N, stream);
    count_deg<<<(R * E + 255) / 256, 256, 0, stream>>>(dst, deg);
    {
        dim3 g(NB, R);
        scanA<<<g, 1024, 0, stream>>>(deg, rowptr, bsum);
        scanB<<<1, 256, 0, stream>>>(bsum, boff);
        scanC<<<g, 1024, 0, stream>>>(rowptr, boff);
    }
    hipMemsetAsync(deg, 0, sizeof(int) * (size_t)R * N, stream);
    scatter_edges<<<(R * E + 255) / 256, 256, 0, stream>>>(src, dst, rowptr, deg, srclist);

    // --- layer 1 ---
    gemm1_pack<<<N / 8, COLS1, 0, stream>>>(x, W1, packed1);
    attn_l1<<<(N * R * 64 + 255) / 256, 256, 0, stream>>>(packed1, al1, ar1, el1, er1);
    edge_w1<<<((R * N + 3) / 4 * 64 + 255) / 256, 256, 0, stream>>>(el1, er1, rowptr, srclist, aw1);
    agg_l1<<<(N * 64 + 255) / 256, 256, 0, stream>>>(packed1, aw1, rowptr, srclist, b1, h1);

    // --- layer 2 ---
    gemm2_pack<<<N / 8, COLS2, 0, stream>>>(h1, W2, packed2);
    attn_l2<<<(N * R * 64 + 255) / 256, 256, 0, stream>>>(packed2, al2, ar2, el2, er2);
    edge_w2<<<((R * N + 3) / 4 * 64 + 255) / 256, 256, 0, stream>>>(el2, er2, rowptr, srclist, aw2);
    agg_l2_final<<<(N * 64 + 255) / 256, 256, 0, stream>>>(packed2, aw2, rowptr, srclist, b2, Wl, bl, out);
}

// Round 4
// 706.811 us; speedup vs baseline: 1.5541x; 1.2171x over previous
//
#include <hip/hip_runtime.h>

constexpr int R = 3;
constexpr int N = 50000;
constexpr int E = 800000;
constexpr int K = 128;        // IN = HEADS*HID = 128 (both GEMM K dims)
constexpr int COLS1 = 384;    // R * HEADS * HID
constexpr int COLS2 = 192;    // R * HID
constexpr int NB = (N + 1023) / 1024;  // scan blocks per relation = 49

// ---------------- bf16 helpers (RNE) ----------------

__device__ inline unsigned short f2bf(float f) {
    unsigned u = __float_as_uint(f);
    u += 0x7FFF + ((u >> 16) & 1);
    return (unsigned short)(u >> 16);
}
__device__ inline float bf2f_lo(unsigned p) { return __uint_as_float(p << 16); }
__device__ inline float bf2f_hi(unsigned p) { return __uint_as_float(p & 0xFFFF0000u); }
__device__ inline float bf2f(unsigned short b) { return __uint_as_float(((unsigned)b) << 16); }

__device__ inline float lrelu02(float x) { return x > 0.f ? x : 0.2f * x; }
__device__ inline float elu1(float x) { return x > 0.f ? x : expm1f(x); }

// ---------------- CSR build ----------------

__global__ void count_deg(const int* __restrict__ dst, int* __restrict__ deg) {
    int idx = blockIdx.x * blockDim.x + threadIdx.x;
    if (idx >= R * E) return;
    int r = idx / E;
    atomicAdd(&deg[r * N + dst[idx]], 1);
}

__global__ __launch_bounds__(1024) void scanA(const int* __restrict__ deg,
                                              int* __restrict__ rowptr,
                                              int* __restrict__ bsum) {
    const int r = blockIdx.y;
    const int b = blockIdx.x;
    const int tid = threadIdx.x;
    const int lane = tid & 63;
    const int w = tid >> 6;
    const int i = b * 1024 + tid;
    int x = (i < N) ? deg[r * N + i] : 0;
#pragma unroll
    for (int off = 1; off < 64; off <<= 1) {
        int t = __shfl_up(x, off);
        if (lane >= off) x += t;
    }
    __shared__ int wsum[16];
    if (lane == 63) wsum[w] = x;
    __syncthreads();
    if (tid < 16) {
        int y = wsum[tid];
#pragma unroll
        for (int off = 1; off < 16; off <<= 1) {
            int t = __shfl_up(y, off);
            if (tid >= off) y += t;
        }
        wsum[tid] = y;
    }
    __syncthreads();
    int incl = x + (w > 0 ? wsum[w - 1] : 0);
    if (i < N) rowptr[r * (N + 1) + i + 1] = incl;
    if (tid == 1023) bsum[r * NB + b] = incl;
}

__global__ void scanB(const int* __restrict__ bsum, int* __restrict__ boff) {
    int w = threadIdx.x >> 6, lane = threadIdx.x & 63;
    if (w >= R) return;
    int v = (lane < NB) ? bsum[w * NB + lane] : 0;
    int incl = v;
#pragma unroll
    for (int off = 1; off < 64; off <<= 1) {
        int t = __shfl_up(incl, off);
        if (lane >= off) incl += t;
    }
    if (lane < NB) boff[w * NB + lane] = incl - v;  // exclusive
}

__global__ __launch_bounds__(1024) void scanC(int* __restrict__ rowptr,
                                              const int* __restrict__ boff) {
    const int r = blockIdx.y;
    const int b = blockIdx.x;
    const int i = b * 1024 + threadIdx.x;
    if (i < N) rowptr[r * (N + 1) + i + 1] += boff[r * NB + b];
    if (i == 0) rowptr[r * (N + 1)] = 0;
}

__global__ void scatter_edges(const int* __restrict__ src, const int* __restrict__ dst,
                              const int* __restrict__ rowptr, int* __restrict__ cursor,
                              int* __restrict__ srclist) {
    int idx = blockIdx.x * blockDim.x + threadIdx.x;
    if (idx >= R * E) return;
    int r = idx / E;
    int d = dst[idx];
    int pos = rowptr[r * (N + 1) + d] + atomicAdd(&cursor[r * N + d], 1);
    srclist[r * E + pos] = src[idx];
}

// ---------------- GEMM1: X[N,128] @ W1[R][128][128] -> packed bf16x2 (head0|head1) ----------------

__global__ __launch_bounds__(COLS1) void gemm1_pack(const float* __restrict__ X,
                                                    const float* __restrict__ W,
                                                    unsigned* __restrict__ packed1) {
    __shared__ float sm[8 * COLS1];
    float* xs = sm;
    const int n0 = blockIdx.x * 8;
    const int c = threadIdx.x;
    for (int t = c; t < 8 * K; t += COLS1)
        xs[t] = X[(size_t)(n0 + (t >> 7)) * K + (t & 127)];
    __syncthreads();
    const int rr = c >> 7;
    const int j = c & 127;
    const float* wp = W + (size_t)rr * (K * 128) + j;
    float acc[8];
#pragma unroll
    for (int b = 0; b < 8; b++) acc[b] = 0.f;
#pragma unroll 8
    for (int k = 0; k < K; k++) {
        float wv = wp[(size_t)k * 128];
#pragma unroll
        for (int b = 0; b < 8; b++) acc[b] += xs[b * 128 + k] * wv;
    }
    __syncthreads();
#pragma unroll
    for (int b = 0; b < 8; b++) sm[b * COLS1 + c] = acc[b];
    __syncthreads();
    if (c < 192) {
        int r = c >> 6, d = c & 63;
#pragma unroll
        for (int b = 0; b < 8; b++) {
            float f0 = sm[b * COLS1 + r * 128 + d];
            float f1 = sm[b * COLS1 + r * 128 + 64 + d];
            packed1[((size_t)(n0 + b) * R + r) * 64 + d] =
                (unsigned)f2bf(f0) | ((unsigned)f2bf(f1) << 16);
        }
    }
}

// ---------------- GEMM2: h1[N,128] @ W2[R][128][64] -> packed bf16 ushort ----------------

__global__ __launch_bounds__(COLS2) void gemm2_pack(const float* __restrict__ X,
                                                    const float* __restrict__ W,
                                                    unsigned short* __restrict__ packed2) {
    __shared__ float xs[8 * K];
    const int n0 = blockIdx.x * 8;
    const int c = threadIdx.x;
    for (int t = c; t < 8 * K; t += COLS2)
        xs[t] = X[(size_t)(n0 + (t >> 7)) * K + (t & 127)];
    __syncthreads();
    const int rr = c >> 6;
    const int j = c & 63;
    const float* wp = W + (size_t)rr * (K * 64) + j;
    float acc[8];
#pragma unroll
    for (int b = 0; b < 8; b++) acc[b] = 0.f;
#pragma unroll 8
    for (int k = 0; k < K; k++) {
        float wv = wp[(size_t)k * 64];
#pragma unroll
        for (int b = 0; b < 8; b++) acc[b] += xs[b * 128 + k] * wv;
    }
#pragma unroll
    for (int b = 0; b < 8; b++)
        packed2[((size_t)(n0 + b) * R + rr) * 64 + j] = f2bf(acc[b]);
}

// ---------------- attention logits ----------------

__global__ void attn_l1(const unsigned* __restrict__ packed1, const float* __restrict__ al1,
                        const float* __restrict__ ar1, float* __restrict__ el,
                        float* __restrict__ er) {
    int w = (blockIdx.x * blockDim.x + threadIdx.x) >> 6;
    int lane = threadIdx.x & 63;
    if (w >= N * R) return;
    int r = w / N;
    int n = w - r * N;
    unsigned p = packed1[((size_t)n * R + r) * 64 + lane];
    float f0 = bf2f_lo(p), f1 = bf2f_hi(p);
    float p00 = f0 * al1[r * 128 + lane];
    float p01 = f0 * ar1[r * 128 + lane];
    float p10 = f1 * al1[r * 128 + 64 + lane];
    float p11 = f1 * ar1[r * 128 + 64 + lane];
#pragma unroll
    for (int off = 32; off; off >>= 1) {
        p00 += __shfl_xor(p00, off);
        p01 += __shfl_xor(p01, off);
        p10 += __shfl_xor(p10, off);
        p11 += __shfl_xor(p11, off);
    }
    if (lane == 0) {
        el[(r * N + n) * 2 + 0] = p00;
        el[(r * N + n) * 2 + 1] = p10;
        er[(r * N + n) * 2 + 0] = p01;
        er[(r * N + n) * 2 + 1] = p11;
    }
}

__global__ void attn_l2(const unsigned short* __restrict__ packed2, const float* __restrict__ al2,
                        const float* __restrict__ ar2, float* __restrict__ el,
                        float* __restrict__ er) {
    int w = (blockIdx.x * blockDim.x + threadIdx.x) >> 6;
    int lane = threadIdx.x & 63;
    if (w >= N * R) return;
    int r = w / N;
    int n = w - r * N;
    float f = bf2f(packed2[((size_t)n * R + r) * 64 + lane]);
    float pl = f * al2[r * 64 + lane];
    float pr = f * ar2[r * 64 + lane];
#pragma unroll
    for (int off = 32; off; off >>= 1) {
        pl += __shfl_xor(pl, off);
        pr += __shfl_xor(pr, off);
    }
    if (lane == 0) {
        el[r * N + n] = pl;
        er[r * N + n] = pr;
    }
}

// ---------------- aggregation: lane-parallel edge prep + deep-unrolled gathers ----------------

__global__ void agg_l1(const unsigned* __restrict__ packed1,
                       const float* __restrict__ el_, const float* __restrict__ er_,
                       const int* __restrict__ rowptr, const int* __restrict__ srclist,
                       const float* __restrict__ b1, float* __restrict__ h1) {
    int n = (blockIdx.x * blockDim.x + threadIdx.x) >> 6;
    int lane = threadIdx.x & 63;
    if (n >= N) return;
    const float2* el2 = (const float2*)el_;
    const float2* er2 = (const float2*)er_;
    float h0 = 0.f, h1v = 0.f;
    for (int r = 0; r < R; r++) {
        int beg = rowptr[r * (N + 1) + n];
        int end = rowptr[r * (N + 1) + n + 1];
        float2 ern = er2[r * N + n];
        const int* sl = srclist + r * E;
        const int rbase = r * N;
        float acc0 = 0.f, acc1 = 0.f, zl0 = 0.f, zl1 = 0.f;
        for (int cbeg = beg; cbeg < end; cbeg += 64) {
            int cnt = min(64, end - cbeg);
            int sid = 0;
            float ew0 = 0.f, ew1 = 0.f;
            if (lane < cnt) {
                sid = sl[cbeg + lane];
                float2 e = el2[rbase + sid];
                ew0 = __expf(lrelu02(e.x + ern.x));
                ew1 = __expf(lrelu02(e.y + ern.y));
            }
            zl0 += ew0;
            zl1 += ew1;
            int k = 0;
            for (; k + 3 < cnt; k += 4) {
                int s0 = __shfl(sid, k), s1 = __shfl(sid, k + 1);
                int s2 = __shfl(sid, k + 2), s3 = __shfl(sid, k + 3);
                float a00 = __shfl(ew0, k), a01 = __shfl(ew0, k + 1);
                float a02 = __shfl(ew0, k + 2), a03 = __shfl(ew0, k + 3);
                float a10 = __shfl(ew1, k), a11 = __shfl(ew1, k + 1);
                float a12 = __shfl(ew1, k + 2), a13 = __shfl(ew1, k + 3);
                unsigned p0 = packed1[((size_t)s0 * R + r) * 64 + lane];
                unsigned p1 = packed1[((size_t)s1 * R + r) * 64 + lane];
                unsigned p2 = packed1[((size_t)s2 * R + r) * 64 + lane];
                unsigned p3 = packed1[((size_t)s3 * R + r) * 64 + lane];
                acc0 += a00 * bf2f_lo(p0) + a01 * bf2f_lo(p1);
                acc1 += a10 * bf2f_hi(p0) + a11 * bf2f_hi(p1);
                acc0 += a02 * bf2f_lo(p2) + a03 * bf2f_lo(p3);
                acc1 += a12 * bf2f_hi(p2) + a13 * bf2f_hi(p3);
            }
            for (; k < cnt; k++) {
                int s = __shfl(sid, k);
                float a0 = __shfl(ew0, k);
                float a1 = __shfl(ew1, k);
                unsigned p = packed1[((size_t)s * R + r) * 64 + lane];
                acc0 += a0 * bf2f_lo(p);
                acc1 += a1 * bf2f_hi(p);
            }
        }
#pragma unroll
        for (int off = 32; off; off >>= 1) {
            zl0 += __shfl_xor(zl0, off);
            zl1 += __shfl_xor(zl1, off);
        }
        float rz0 = (end > beg) ? 1.f / zl0 : 0.f;
        float rz1 = (end > beg) ? 1.f / zl1 : 0.f;
        h0 += elu1(acc0 * rz0 + b1[r * 128 + lane]);
        h1v += elu1(acc1 * rz1 + b1[r * 128 + 64 + lane]);
    }
    h1[(size_t)n * 128 + lane] = h0;
    h1[(size_t)n * 128 + 64 + lane] = h1v;
}

// agg layer2 fused with final linear (Wl staged in LDS)
__global__ __launch_bounds__(256) void agg_l2_final(const unsigned short* __restrict__ packed2,
                                                    const float* __restrict__ el,
                                                    const float* __restrict__ er,
                                                    const int* __restrict__ rowptr,
                                                    const int* __restrict__ srclist,
                                                    const float* __restrict__ b2,
                                                    const float* __restrict__ Wl,
                                                    const float* __restrict__ bl,
                                                    float* __restrict__ out) {
    __shared__ float wl_s[64 * 64];
    for (int t = threadIdx.x; t < 64 * 64; t += 256) wl_s[t] = Wl[t];
    __syncthreads();
    int n = (blockIdx.x * blockDim.x + threadIdx.x) >> 6;
    int lane = threadIdx.x & 63;
    if (n >= N) return;
    float hacc = 0.f;
    for (int r = 0; r < R; r++) {
        int beg = rowptr[r * (N + 1) + n];
        int end = rowptr[r * (N + 1) + n + 1];
        float ern = er[r * N + n];
        const int* sl = srclist + r * E;
        const int rbase = r * N;
        float acc = 0.f, zl = 0.f;
        for (int cbeg = beg; cbeg < end; cbeg += 64) {
            int cnt = min(64, end - cbeg);
            int sid = 0;
            float ew = 0.f;
            if (lane < cnt) {
                sid = sl[cbeg + lane];
                ew = __expf(lrelu02(el[rbase + sid] + ern));
            }
            zl += ew;
            int k = 0;
            for (; k + 3 < cnt; k += 4) {
                int s0 = __shfl(sid, k), s1 = __shfl(sid, k + 1);
                int s2 = __shfl(sid, k + 2), s3 = __shfl(sid, k + 3);
                float a0 = __shfl(ew, k), a1 = __shfl(ew, k + 1);
                float a2 = __shfl(ew, k + 2), a3 = __shfl(ew, k + 3);
                float f0 = bf2f(packed2[((size_t)s0 * R + r) * 64 + lane]);
                float f1 = bf2f(packed2[((size_t)s1 * R + r) * 64 + lane]);
                float f2 = bf2f(packed2[((size_t)s2 * R + r) * 64 + lane]);
                float f3 = bf2f(packed2[((size_t)s3 * R + r) * 64 + lane]);
                acc += a0 * f0 + a1 * f1 + a2 * f2 + a3 * f3;
            }
            for (; k < cnt; k++) {
                int s = __shfl(sid, k);
                float a = __shfl(ew, k);
                acc += a * bf2f(packed2[((size_t)s * R + r) * 64 + lane]);
            }
        }
#pragma unroll
        for (int off = 32; off; off >>= 1) zl += __shfl_xor(zl, off);
        float rz = (end > beg) ? 1.f / zl : 0.f;
        hacc += elu1(acc * rz + b2[r * 64 + lane]);
    }
    float res = bl[lane];
#pragma unroll
    for (int kk = 0; kk < 64; kk++) {
        float xk = __shfl(hacc, kk);
        res += xk * wl_s[kk * 64 + lane];
    }
    out[(size_t)n * 64 + lane] = res;
}

// ---------------- launch ----------------

extern "C" void kernel_launch(void* const* d_in, const int* in_sizes, int n_in,
                              void* d_out, int out_size, void* d_ws, size_t ws_size,
                              hipStream_t stream) {
    const float* x   = (const float*)d_in[0];
    const int*   src = (const int*)d_in[1];
    const int*   dst = (const int*)d_in[2];
    const float* W1  = (const float*)d_in[3];
    const float* al1 = (const float*)d_in[4];
    const float* ar1 = (const float*)d_in[5];
    const float* b1  = (const float*)d_in[6];
    const float* W2  = (const float*)d_in[7];
    const float* al2 = (const float*)d_in[8];
    const float* ar2 = (const float*)d_in[9];
    const float* b2  = (const float*)d_in[10];
    const float* Wl  = (const float*)d_in[11];
    const float* bl  = (const float*)d_in[12];
    float* out = (float*)d_out;

    char* ws = (char*)d_ws;
    size_t off = 0;
    auto alloc = [&](size_t bytes) {
        char* p = ws + off;
        off += (bytes + 255) & ~(size_t)255;
        return p;
    };
    unsigned*       packed1 = (unsigned*)alloc(sizeof(unsigned) * (size_t)N * R * 64);
    unsigned short* packed2 = (unsigned short*)alloc(sizeof(unsigned short) * (size_t)N * R * 64);
    float* h1      = (float*)alloc(sizeof(float) * (size_t)N * 128);
    float* el1     = (float*)alloc(sizeof(float) * (size_t)R * N * 2);
    float* er1     = (float*)alloc(sizeof(float) * (size_t)R * N * 2);
    float* el2     = (float*)alloc(sizeof(float) * (size_t)R * N);
    float* er2     = (float*)alloc(sizeof(float) * (size_t)R * N);
    int*   rowptr  = (int*)alloc(sizeof(int) * (size_t)R * (N + 1));
    int*   deg     = (int*)alloc(sizeof(int) * (size_t)R * N);
    int*   srclist = (int*)alloc(sizeof(int) * (size_t)R * E);
    int*   bsum    = (int*)alloc(sizeof(int) * (size_t)R * NB);
    int*   boff    = (int*)alloc(sizeof(int) * (size_t)R * NB);

    // --- CSR build (shared by both layers) ---
    hipMemsetAsync(deg, 0, sizeof(int) * (size_t)R * N, stream);
    count_deg<<<(R * E + 255) / 256, 256, 0, stream>>>(dst, deg);
    {
        dim3 g(NB, R);
        scanA<<<g, 1024, 0, stream>>>(deg, rowptr, bsum);
        scanB<<<1, 256, 0, stream>>>(bsum, boff);
        scanC<<<g, 1024, 0, stream>>>(rowptr, boff);
    }
    hipMemsetAsync(deg, 0, sizeof(int) * (size_t)R * N, stream);
    scatter_edges<<<(R * E + 255) / 256, 256, 0, stream>>>(src, dst, rowptr, deg, srclist);

    // --- layer 1 ---
    gemm1_pack<<<N / 8, COLS1, 0, stream>>>(x, W1, packed1);
    attn_l1<<<(N * R * 64 + 255) / 256, 256, 0, stream>>>(packed1, al1, ar1, el1, er1);
    agg_l1<<<(N * 64 + 255) / 256, 256, 0, stream>>>(packed1, el1, er1, rowptr, srclist, b1, h1);

    // --- layer 2 ---
    gemm2_pack<<<N / 8, COLS2, 0, stream>>>(h1, W2, packed2);
    attn_l2<<<(N * R * 64 + 255) / 256, 256, 0, stream>>>(packed2, al2, ar2, el2, er2);
    agg_l2_final<<<(N * 64 + 255) / 256, 256, 0, stream>>>(packed2, el2, er2, rowptr, srclist, b2, Wl, bl, out);
}

// Round 5
// 675.840 us; speedup vs baseline: 1.6253x; 1.0458x over previous
//
#include <hip/hip_runtime.h>

constexpr int R = 3;
constexpr int N = 50000;
constexpr int E = 800000;
constexpr int K = 128;        // IN = HEADS*HID = 128 (both GEMM K dims)
constexpr int COLS1 = 384;    // R * HEADS * HID
constexpr int COLS2 = 192;    // R * HID
constexpr int NB = (N + 1023) / 1024;  // scan blocks per relation = 49
constexpr int NT16 = N / 16;           // 3125 node-tiles for MFMA GEMMs

typedef __attribute__((ext_vector_type(8))) short bf16x8;
typedef __attribute__((ext_vector_type(4))) float f32x4;

// ---------------- bf16 helpers (RNE) ----------------

__device__ inline unsigned short f2bf(float f) {
    unsigned u = __float_as_uint(f);
    u += 0x7FFF + ((u >> 16) & 1);
    return (unsigned short)(u >> 16);
}
__device__ inline float bf2f_lo(unsigned p) { return __uint_as_float(p << 16); }
__device__ inline float bf2f_hi(unsigned p) { return __uint_as_float(p & 0xFFFF0000u); }
__device__ inline float bf2f(unsigned short b) { return __uint_as_float(((unsigned)b) << 16); }

__device__ inline float lrelu02(float x) { return x > 0.f ? x : 0.2f * x; }
__device__ inline float elu1(float x) { return x > 0.f ? x : expm1f(x); }

// ---------------- CSR build ----------------

__global__ void count_deg(const int* __restrict__ dst, int* __restrict__ deg) {
    int idx = blockIdx.x * blockDim.x + threadIdx.x;
    if (idx >= R * E) return;
    int r = idx / E;
    atomicAdd(&deg[r * N + dst[idx]], 1);
}

__global__ __launch_bounds__(1024) void scanA(const int* __restrict__ deg,
                                              int* __restrict__ rowptr,
                                              int* __restrict__ bsum) {
    const int r = blockIdx.y;
    const int b = blockIdx.x;
    const int tid = threadIdx.x;
    const int lane = tid & 63;
    const int w = tid >> 6;
    const int i = b * 1024 + tid;
    int x = (i < N) ? deg[r * N + i] : 0;
#pragma unroll
    for (int off = 1; off < 64; off <<= 1) {
        int t = __shfl_up(x, off);
        if (lane >= off) x += t;
    }
    __shared__ int wsum[16];
    if (lane == 63) wsum[w] = x;
    __syncthreads();
    if (tid < 16) {
        int y = wsum[tid];
#pragma unroll
        for (int off = 1; off < 16; off <<= 1) {
            int t = __shfl_up(y, off);
            if (tid >= off) y += t;
        }
        wsum[tid] = y;
    }
    __syncthreads();
    int incl = x + (w > 0 ? wsum[w - 1] : 0);
    if (i < N) rowptr[r * (N + 1) + i + 1] = incl;
    if (tid == 1023) bsum[r * NB + b] = incl;
}

__global__ void scanB(const int* __restrict__ bsum, int* __restrict__ boff) {
    int w = threadIdx.x >> 6, lane = threadIdx.x & 63;
    if (w >= R) return;
    int v = (lane < NB) ? bsum[w * NB + lane] : 0;
    int incl = v;
#pragma unroll
    for (int off = 1; off < 64; off <<= 1) {
        int t = __shfl_up(incl, off);
        if (lane >= off) incl += t;
    }
    if (lane < NB) boff[w * NB + lane] = incl - v;  // exclusive
}

__global__ __launch_bounds__(1024) void scanC(int* __restrict__ rowptr,
                                              const int* __restrict__ boff) {
    const int r = blockIdx.y;
    const int b = blockIdx.x;
    const int i = b * 1024 + threadIdx.x;
    if (i < N) rowptr[r * (N + 1) + i + 1] += boff[r * NB + b];
    if (i == 0) rowptr[r * (N + 1)] = 0;
}

__global__ void scatter_edges(const int* __restrict__ src, const int* __restrict__ dst,
                              const int* __restrict__ rowptr, int* __restrict__ cursor,
                              int* __restrict__ srclist) {
    int idx = blockIdx.x * blockDim.x + threadIdx.x;
    if (idx >= R * E) return;
    int r = idx / E;
    int d = dst[idx];
    int pos = rowptr[r * (N + 1) + d] + atomicAdd(&cursor[r * N + d], 1);
    srclist[r * E + pos] = src[idx];
}

// ---------------- W prep: transpose to [col][k] and split hi/lo bf16 ----------------

__global__ __launch_bounds__(128) void prep_w(const float* __restrict__ W1,
                                              const float* __restrict__ W2,
                                              short* __restrict__ Wt1H, short* __restrict__ Wt1L,
                                              short* __restrict__ Wt2H, short* __restrict__ Wt2L) {
    int b = blockIdx.x;
    int k = threadIdx.x;
    if (b < COLS1) {
        int r = b >> 7, col = b & 127;
        float v = W1[(size_t)r * 128 * 128 + (size_t)k * 128 + col];
        unsigned short h = f2bf(v);
        Wt1H[(size_t)b * K + k] = (short)h;
        Wt1L[(size_t)b * K + k] = (short)f2bf(v - bf2f(h));
    } else {
        int b2 = b - COLS1;
        int r = b2 >> 6, col = b2 & 63;
        float v = W2[(size_t)r * 128 * 64 + (size_t)k * 64 + col];
        unsigned short h = f2bf(v);
        Wt2H[(size_t)b2 * K + k] = (short)h;
        Wt2L[(size_t)b2 * K + k] = (short)f2bf(v - bf2f(h));
    }
}

// ---------------- MFMA GEMM1: X[N,128] @ W1 -> packed1 bf16x2 (head0|head1) ----------------
// One wave per 16-node tile; A (x) split hi/lo on the fly; W pre-split.
// Slot mapping for A and B fragments: k = (lane>>4)*8 + i  (same bijection both sides).

__device__ inline void split_a(const float* __restrict__ xrow, bf16x8* ah, bf16x8* al) {
#pragma unroll
    for (int ks = 0; ks < 4; ks++) {
        f32x4 xa = *(const f32x4*)(xrow + ks * 32);
        f32x4 xb = *(const f32x4*)(xrow + ks * 32 + 4);
#pragma unroll
        for (int i = 0; i < 4; i++) {
            unsigned short h = f2bf(xa[i]);
            ah[ks][i] = (short)h;
            al[ks][i] = (short)f2bf(xa[i] - bf2f(h));
            unsigned short h2 = f2bf(xb[i]);
            ah[ks][4 + i] = (short)h2;
            al[ks][4 + i] = (short)f2bf(xb[i] - bf2f(h2));
        }
    }
}

__global__ __launch_bounds__(256) void gemm1_mfma(const float* __restrict__ X,
                                                  const short* __restrict__ WtH,
                                                  const short* __restrict__ WtL,
                                                  unsigned* __restrict__ packed1) {
    int wid = (blockIdx.x * 256 + threadIdx.x) >> 6;
    if (wid >= NT16) return;
    const int lane = threadIdx.x & 63;
    const int c = lane & 15;
    const int g = lane >> 4;
    const int n0 = wid * 16;
    bf16x8 ah[4], al[4];
    split_a(X + (size_t)(n0 + c) * K + g * 8, ah, al);
    for (int r = 0; r < R; r++) {
        for (int tr = 0; tr < 4; tr++) {
            const short* bh = WtH + (size_t)(r * 128 + tr * 16 + c) * K + g * 8;
            const short* bl = WtL + (size_t)(r * 128 + tr * 16 + c) * K + g * 8;
            f32x4 acc0 = {0.f, 0.f, 0.f, 0.f};
            f32x4 acc1 = {0.f, 0.f, 0.f, 0.f};
#pragma unroll
            for (int ks = 0; ks < 4; ks++) {
                bf16x8 b0h = *(const bf16x8*)(bh + ks * 32);
                bf16x8 b0l = *(const bf16x8*)(bl + ks * 32);
                bf16x8 b1h = *(const bf16x8*)(bh + 64 * K + ks * 32);
                bf16x8 b1l = *(const bf16x8*)(bl + 64 * K + ks * 32);
                acc0 = __builtin_amdgcn_mfma_f32_16x16x32_bf16(ah[ks], b0h, acc0, 0, 0, 0);
                acc0 = __builtin_amdgcn_mfma_f32_16x16x32_bf16(al[ks], b0h, acc0, 0, 0, 0);
                acc0 = __builtin_amdgcn_mfma_f32_16x16x32_bf16(ah[ks], b0l, acc0, 0, 0, 0);
                acc1 = __builtin_amdgcn_mfma_f32_16x16x32_bf16(ah[ks], b1h, acc1, 0, 0, 0);
                acc1 = __builtin_amdgcn_mfma_f32_16x16x32_bf16(al[ks], b1h, acc1, 0, 0, 0);
                acc1 = __builtin_amdgcn_mfma_f32_16x16x32_bf16(ah[ks], b1l, acc1, 0, 0, 0);
            }
#pragma unroll
            for (int i = 0; i < 4; i++) {
                int m = g * 4 + i;
                unsigned wrd = (unsigned)f2bf(acc0[i]) | ((unsigned)f2bf(acc1[i]) << 16);
                packed1[(size_t)(n0 + m) * 192 + r * 64 + tr * 16 + c] = wrd;
            }
        }
    }
}

// ---------------- MFMA GEMM2: h1[N,128] @ W2 -> packed2 bf16 ushort ----------------

__global__ __launch_bounds__(256) void gemm2_mfma(const float* __restrict__ X,
                                                  const short* __restrict__ WtH,
                                                  const short* __restrict__ WtL,
                                                  unsigned short* __restrict__ packed2) {
    int wid = (blockIdx.x * 256 + threadIdx.x) >> 6;
    if (wid >= NT16) return;
    const int lane = threadIdx.x & 63;
    const int c = lane & 15;
    const int g = lane >> 4;
    const int n0 = wid * 16;
    bf16x8 ah[4], al[4];
    split_a(X + (size_t)(n0 + c) * K + g * 8, ah, al);
    for (int t = 0; t < 12; t++) {
        const short* bh = WtH + (size_t)(t * 16 + c) * K + g * 8;
        const short* bl = WtL + (size_t)(t * 16 + c) * K + g * 8;
        f32x4 acc = {0.f, 0.f, 0.f, 0.f};
#pragma unroll
        for (int ks = 0; ks < 4; ks++) {
            bf16x8 vh = *(const bf16x8*)(bh + ks * 32);
            bf16x8 vl = *(const bf16x8*)(bl + ks * 32);
            acc = __builtin_amdgcn_mfma_f32_16x16x32_bf16(ah[ks], vh, acc, 0, 0, 0);
            acc = __builtin_amdgcn_mfma_f32_16x16x32_bf16(al[ks], vh, acc, 0, 0, 0);
            acc = __builtin_amdgcn_mfma_f32_16x16x32_bf16(ah[ks], vl, acc, 0, 0, 0);
        }
#pragma unroll
        for (int i = 0; i < 4; i++) {
            int m = g * 4 + i;
            packed2[(size_t)(n0 + m) * 192 + t * 16 + c] = f2bf(acc[i]);
        }
    }
}

// ---------------- attention logits ----------------

__global__ void attn_l1(const unsigned* __restrict__ packed1, const float* __restrict__ al1,
                        const float* __restrict__ ar1, float* __restrict__ el,
                        float* __restrict__ er) {
    int w = (blockIdx.x * blockDim.x + threadIdx.x) >> 6;
    int lane = threadIdx.x & 63;
    if (w >= N * R) return;
    int r = w / N;
    int n = w - r * N;
    unsigned p = packed1[((size_t)n * R + r) * 64 + lane];
    float f0 = bf2f_lo(p), f1 = bf2f_hi(p);
    float p00 = f0 * al1[r * 128 + lane];
    float p01 = f0 * ar1[r * 128 + lane];
    float p10 = f1 * al1[r * 128 + 64 + lane];
    float p11 = f1 * ar1[r * 128 + 64 + lane];
#pragma unroll
    for (int off = 32; off; off >>= 1) {
        p00 += __shfl_xor(p00, off);
        p01 += __shfl_xor(p01, off);
        p10 += __shfl_xor(p10, off);
        p11 += __shfl_xor(p11, off);
    }
    if (lane == 0) {
        el[(r * N + n) * 2 + 0] = p00;
        el[(r * N + n) * 2 + 1] = p10;
        er[(r * N + n) * 2 + 0] = p01;
        er[(r * N + n) * 2 + 1] = p11;
    }
}

__global__ void attn_l2(const unsigned short* __restrict__ packed2, const float* __restrict__ al2,
                        const float* __restrict__ ar2, float* __restrict__ el,
                        float* __restrict__ er) {
    int w = (blockIdx.x * blockDim.x + threadIdx.x) >> 6;
    int lane = threadIdx.x & 63;
    if (w >= N * R) return;
    int r = w / N;
    int n = w - r * N;
    float f = bf2f(packed2[((size_t)n * R + r) * 64 + lane]);
    float pl = f * al2[r * 64 + lane];
    float pr = f * ar2[r * 64 + lane];
#pragma unroll
    for (int off = 32; off; off >>= 1) {
        pl += __shfl_xor(pl, off);
        pr += __shfl_xor(pr, off);
    }
    if (lane == 0) {
        el[r * N + n] = pl;
        er[r * N + n] = pr;
    }
}

// ---------------- aggregation: lane-parallel edge prep + deep-unrolled gathers ----------------

__global__ void agg_l1(const unsigned* __restrict__ packed1,
                       const float* __restrict__ el_, const float* __restrict__ er_,
                       const int* __restrict__ rowptr, const int* __restrict__ srclist,
                       const float* __restrict__ b1, float* __restrict__ h1) {
    int n = (blockIdx.x * blockDim.x + threadIdx.x) >> 6;
    int lane = threadIdx.x & 63;
    if (n >= N) return;
    const float2* el2 = (const float2*)el_;
    const float2* er2 = (const float2*)er_;
    float h0 = 0.f, h1v = 0.f;
    for (int r = 0; r < R; r++) {
        int beg = rowptr[r * (N + 1) + n];
        int end = rowptr[r * (N + 1) + n + 1];
        float2 ern = er2[r * N + n];
        const int* sl = srclist + r * E;
        const int rbase = r * N;
        float acc0 = 0.f, acc1 = 0.f, zl0 = 0.f, zl1 = 0.f;
        for (int cbeg = beg; cbeg < end; cbeg += 64) {
            int cnt = min(64, end - cbeg);
            int sid = 0;
            float ew0 = 0.f, ew1 = 0.f;
            if (lane < cnt) {
                sid = sl[cbeg + lane];
                float2 e = el2[rbase + sid];
                ew0 = __expf(lrelu02(e.x + ern.x));
                ew1 = __expf(lrelu02(e.y + ern.y));
            }
            zl0 += ew0;
            zl1 += ew1;
            int k = 0;
            for (; k + 3 < cnt; k += 4) {
                int s0 = __shfl(sid, k), s1 = __shfl(sid, k + 1);
                int s2 = __shfl(sid, k + 2), s3 = __shfl(sid, k + 3);
                float a00 = __shfl(ew0, k), a01 = __shfl(ew0, k + 1);
                float a02 = __shfl(ew0, k + 2), a03 = __shfl(ew0, k + 3);
                float a10 = __shfl(ew1, k), a11 = __shfl(ew1, k + 1);
                float a12 = __shfl(ew1, k + 2), a13 = __shfl(ew1, k + 3);
                unsigned p0 = packed1[((size_t)s0 * R + r) * 64 + lane];
                unsigned p1 = packed1[((size_t)s1 * R + r) * 64 + lane];
                unsigned p2 = packed1[((size_t)s2 * R + r) * 64 + lane];
                unsigned p3 = packed1[((size_t)s3 * R + r) * 64 + lane];
                acc0 += a00 * bf2f_lo(p0) + a01 * bf2f_lo(p1);
                acc1 += a10 * bf2f_hi(p0) + a11 * bf2f_hi(p1);
                acc0 += a02 * bf2f_lo(p2) + a03 * bf2f_lo(p3);
                acc1 += a12 * bf2f_hi(p2) + a13 * bf2f_hi(p3);
            }
            for (; k < cnt; k++) {
                int s = __shfl(sid, k);
                float a0 = __shfl(ew0, k);
                float a1 = __shfl(ew1, k);
                unsigned p = packed1[((size_t)s * R + r) * 64 + lane];
                acc0 += a0 * bf2f_lo(p);
                acc1 += a1 * bf2f_hi(p);
            }
        }
#pragma unroll
        for (int off = 32; off; off >>= 1) {
            zl0 += __shfl_xor(zl0, off);
            zl1 += __shfl_xor(zl1, off);
        }
        float rz0 = (end > beg) ? 1.f / zl0 : 0.f;
        float rz1 = (end > beg) ? 1.f / zl1 : 0.f;
        h0 += elu1(acc0 * rz0 + b1[r * 128 + lane]);
        h1v += elu1(acc1 * rz1 + b1[r * 128 + 64 + lane]);
    }
    h1[(size_t)n * 128 + lane] = h0;
    h1[(size_t)n * 128 + 64 + lane] = h1v;
}

// agg layer2 fused with final linear (Wl staged in LDS)
__global__ __launch_bounds__(256) void agg_l2_final(const unsigned short* __restrict__ packed2,
                                                    const float* __restrict__ el,
                                                    const float* __restrict__ er,
                                                    const int* __restrict__ rowptr,
                                                    const int* __restrict__ srclist,
                                                    const float* __restrict__ b2,
                                                    const float* __restrict__ Wl,
                                                    const float* __restrict__ bl,
                                                    float* __restrict__ out) {
    __shared__ float wl_s[64 * 64];
    for (int t = threadIdx.x; t < 64 * 64; t += 256) wl_s[t] = Wl[t];
    __syncthreads();
    int n = (blockIdx.x * blockDim.x + threadIdx.x) >> 6;
    int lane = threadIdx.x & 63;
    if (n >= N) return;
    float hacc = 0.f;
    for (int r = 0; r < R; r++) {
        int beg = rowptr[r * (N + 1) + n];
        int end = rowptr[r * (N + 1) + n + 1];
        float ern = er[r * N + n];
        const int* sl = srclist + r * E;
        const int rbase = r * N;
        float acc = 0.f, zl = 0.f;
        for (int cbeg = beg; cbeg < end; cbeg += 64) {
            int cnt = min(64, end - cbeg);
            int sid = 0;
            float ew = 0.f;
            if (lane < cnt) {
                sid = sl[cbeg + lane];
                ew = __expf(lrelu02(el[rbase + sid] + ern));
            }
            zl += ew;
            int k = 0;
            for (; k + 3 < cnt; k += 4) {
                int s0 = __shfl(sid, k), s1 = __shfl(sid, k + 1);
                int s2 = __shfl(sid, k + 2), s3 = __shfl(sid, k + 3);
                float a0 = __shfl(ew, k), a1 = __shfl(ew, k + 1);
                float a2 = __shfl(ew, k + 2), a3 = __shfl(ew, k + 3);
                float f0 = bf2f(packed2[((size_t)s0 * R + r) * 64 + lane]);
                float f1 = bf2f(packed2[((size_t)s1 * R + r) * 64 + lane]);
                float f2 = bf2f(packed2[((size_t)s2 * R + r) * 64 + lane]);
                float f3 = bf2f(packed2[((size_t)s3 * R + r) * 64 + lane]);
                acc += a0 * f0 + a1 * f1 + a2 * f2 + a3 * f3;
            }
            for (; k < cnt; k++) {
                int s = __shfl(sid, k);
                float a = __shfl(ew, k);
                acc += a * bf2f(packed2[((size_t)s * R + r) * 64 + lane]);
            }
        }
#pragma unroll
        for (int off = 32; off; off >>= 1) zl += __shfl_xor(zl, off);
        float rz = (end > beg) ? 1.f / zl : 0.f;
        hacc += elu1(acc * rz + b2[r * 64 + lane]);
    }
    float res = bl[lane];
#pragma unroll
    for (int kk = 0; kk < 64; kk++) {
        float xk = __shfl(hacc, kk);
        res += xk * wl_s[kk * 64 + lane];
    }
    out[(size_t)n * 64 + lane] = res;
}

// ---------------- launch ----------------

extern "C" void kernel_launch(void* const* d_in, const int* in_sizes, int n_in,
                              void* d_out, int out_size, void* d_ws, size_t ws_size,
                              hipStream_t stream) {
    const float* x   = (const float*)d_in[0];
    const int*   src = (const int*)d_in[1];
    const int*   dst = (const int*)d_in[2];
    const float* W1  = (const float*)d_in[3];
    const float* al1 = (const float*)d_in[4];
    const float* ar1 = (const float*)d_in[5];
    const float* b1  = (const float*)d_in[6];
    const float* W2  = (const float*)d_in[7];
    const float* al2 = (const float*)d_in[8];
    const float* ar2 = (const float*)d_in[9];
    const float* b2  = (const float*)d_in[10];
    const float* Wl  = (const float*)d_in[11];
    const float* bl  = (const float*)d_in[12];
    float* out = (float*)d_out;

    char* ws = (char*)d_ws;
    size_t off = 0;
    auto alloc = [&](size_t bytes) {
        char* p = ws + off;
        off += (bytes + 255) & ~(size_t)255;
        return p;
    };
    unsigned*       packed1 = (unsigned*)alloc(sizeof(unsigned) * (size_t)N * R * 64);
    unsigned short* packed2 = (unsigned short*)alloc(sizeof(unsigned short) * (size_t)N * R * 64);
    float* h1      = (float*)alloc(sizeof(float) * (size_t)N * 128);
    float* el1     = (float*)alloc(sizeof(float) * (size_t)R * N * 2);
    float* er1     = (float*)alloc(sizeof(float) * (size_t)R * N * 2);
    float* el2     = (float*)alloc(sizeof(float) * (size_t)R * N);
    float* er2     = (float*)alloc(sizeof(float) * (size_t)R * N);
    int*   rowptr  = (int*)alloc(sizeof(int) * (size_t)R * (N + 1));
    int*   deg     = (int*)alloc(sizeof(int) * (size_t)R * N);
    int*   srclist = (int*)alloc(sizeof(int) * (size_t)R * E);
    int*   bsum    = (int*)alloc(sizeof(int) * (size_t)R * NB);
    int*   boff    = (int*)alloc(sizeof(int) * (size_t)R * NB);
    short* Wt1H    = (short*)alloc(sizeof(short) * (size_t)COLS1 * K);
    short* Wt1L    = (short*)alloc(sizeof(short) * (size_t)COLS1 * K);
    short* Wt2H    = (short*)alloc(sizeof(short) * (size_t)COLS2 * K);
    short* Wt2L    = (short*)alloc(sizeof(short) * (size_t)COLS2 * K);

    // --- W prep (independent; run first) ---
    prep_w<<<COLS1 + COLS2, 128, 0, stream>>>(W1, W2, Wt1H, Wt1L, Wt2H, Wt2L);

    // --- CSR build (shared by both layers) ---
    hipMemsetAsync(deg, 0, sizeof(int) * (size_t)R * N, stream);
    count_deg<<<(R * E + 255) / 256, 256, 0, stream>>>(dst, deg);
    {
        dim3 g(NB, R);
        scanA<<<g, 1024, 0, stream>>>(deg, rowptr, bsum);
        scanB<<<1, 256, 0, stream>>>(bsum, boff);
        scanC<<<g, 1024, 0, stream>>>(rowptr, boff);
    }
    hipMemsetAsync(deg, 0, sizeof(int) * (size_t)R * N, stream);
    scatter_edges<<<(R * E + 255) / 256, 256, 0, stream>>>(src, dst, rowptr, deg, srclist);

    // --- layer 1 ---
    gemm1_mfma<<<(NT16 * 64 + 255) / 256, 256, 0, stream>>>(x, Wt1H, Wt1L, packed1);
    attn_l1<<<(N * R * 64 + 255) / 256, 256, 0, stream>>>(packed1, al1, ar1, el1, er1);
    agg_l1<<<(N * 64 + 255) / 256, 256, 0, stream>>>(packed1, el1, er1, rowptr, srclist, b1, h1);

    // --- layer 2 ---
    gemm2_mfma<<<(NT16 * 64 + 255) / 256, 256, 0, stream>>>(h1, Wt2H, Wt2L, packed2);
    attn_l2<<<(N * R * 64 + 255) / 256, 256, 0, stream>>>(packed2, al2, ar2, el2, er2);
    agg_l2_final<<<(N * 64 + 255) / 256, 256, 0, stream>>>(packed2, el2, er2, rowptr, srclist, b2, Wl, bl, out);
}

// Round 6
// 433.837 us; speedup vs baseline: 2.5319x; 1.5578x over previous
//
#include <hip/hip_runtime.h>

constexpr int R = 3;
constexpr int N = 50000;
constexpr int E = 800000;
constexpr int K = 128;        // IN = HEADS*HID = 128 (both GEMM K dims)
constexpr int COLS1 = 384;    // R * HEADS * HID
constexpr int COLS2 = 192;    // R * HID
constexpr int NT16 = N / 16;  // 3125 node-tiles for MFMA GEMMs

// bucketed CSR build
constexpr int BKT_SH = 9;                    // 512 nodes per bucket
constexpr int NBKT = (N + 511) >> 9;         // 98 buckets per relation
constexpr int BCAP = 10240;                  // bucket capacity (avg 8163, +23 sigma)
constexpr int P1E = 4096;                    // edges per pass-1 block
constexpr int P1B = (E + P1E - 1) / P1E;     // 196 blocks per relation

typedef __attribute__((ext_vector_type(8))) short bf16x8;
typedef __attribute__((ext_vector_type(4))) float f32x4;

// ---------------- bf16 helpers (RNE) ----------------

__device__ inline unsigned short f2bf(float f) {
    unsigned u = __float_as_uint(f);
    u += 0x7FFF + ((u >> 16) & 1);
    return (unsigned short)(u >> 16);
}
__device__ inline float bf2f_lo(unsigned p) { return __uint_as_float(p << 16); }
__device__ inline float bf2f_hi(unsigned p) { return __uint_as_float(p & 0xFFFF0000u); }
__device__ inline float bf2f(unsigned short b) { return __uint_as_float(((unsigned)b) << 16); }

__device__ inline float lrelu02(float x) { return x > 0.f ? x : 0.2f * x; }
__device__ inline float elu1(float x) { return x > 0.f ? x : expm1f(x); }

// ---------------- CSR build: pass 1 (bucket scatter, coalesced) ----------------

__global__ __launch_bounds__(256) void bucket_p1(const int* __restrict__ src,
                                                 const int* __restrict__ dst,
                                                 int* __restrict__ gcur,
                                                 uint2* __restrict__ ebuf) {
    __shared__ uint2 img[P1E];                 // 32 KB
    __shared__ int bins[NBKT], bstart[NBKT], gbase[NBKT];
    __shared__ int sc[128];
    const int r = blockIdx.y;
    const int e0 = blockIdx.x * P1E;
    const int cnt = min(P1E, E - e0);
    const int tid = threadIdx.x;
    if (tid < NBKT) bins[tid] = 0;
    __syncthreads();
    int sv[16], dv[16], rk[16];
    int ni = 0;
    for (int i = tid; i < cnt; i += 256, ni++) {
        sv[ni] = src[(size_t)r * E + e0 + i];
        dv[ni] = dst[(size_t)r * E + e0 + i];
        rk[ni] = atomicAdd(&bins[dv[ni] >> BKT_SH], 1);
    }
    __syncthreads();
    // exclusive scan of bins -> bstart
    if (tid < 128) sc[tid] = (tid < NBKT) ? bins[tid] : 0;
    __syncthreads();
    for (int off = 1; off < 128; off <<= 1) {
        int v = 0;
        if (tid < 128 && tid >= off) v = sc[tid - off];
        __syncthreads();
        if (tid < 128) sc[tid] += v;
        __syncthreads();
    }
    if (tid < NBKT) bstart[tid] = sc[tid] - bins[tid];
    __syncthreads();
    for (int j = 0; j < ni; j++) {
        int b = dv[j] >> BKT_SH;
        img[bstart[b] + rk[j]] = make_uint2((unsigned)sv[j], (unsigned)dv[j]);
    }
    if (tid < NBKT) gbase[tid] = bins[tid] ? atomicAdd(&gcur[r * NBKT + tid], bins[tid]) : 0;
    __syncthreads();
    for (int i = tid; i < cnt; i += 256) {
        uint2 e = img[i];
        int b = (int)(e.y >> BKT_SH);
        int pos = gbase[b] + (i - bstart[b]);
        if (pos < BCAP) ebuf[(size_t)(r * NBKT + b) * BCAP + pos] = e;
    }
}

// exclusive scan of bucket counts -> per-relation bucket prefix
__global__ void bucket_scan(const int* __restrict__ gcur, int* __restrict__ bpre) {
    int w = threadIdx.x >> 6, lane = threadIdx.x & 63;
    if (w >= R) return;
    const int* g = gcur + w * NBKT;
    int* p = bpre + w * NBKT;
    int carry = 0;
    for (int base = 0; base < NBKT; base += 64) {
        int v = (base + lane < NBKT) ? g[base + lane] : 0;
        int x = v;
#pragma unroll
        for (int off = 1; off < 64; off <<= 1) {
            int t = __shfl_up(x, off);
            if (lane >= off) x += t;
        }
        if (base + lane < NBKT) p[base + lane] = carry + x - v;
        carry += __shfl(x, 63);
    }
}

// ---------------- CSR build: pass 2 (per-bucket node sort, writes rowptr + srclist) ----------------

__global__ __launch_bounds__(256) void bucket_p2(const uint2* __restrict__ ebuf,
                                                 const int* __restrict__ gcur,
                                                 const int* __restrict__ bpre,
                                                 int* __restrict__ rowptr,
                                                 int* __restrict__ srclist) {
    __shared__ unsigned img[BCAP];             // 40 KB
    __shared__ int bins[512], bst[512], cur[512], sc[256];
    const int r = blockIdx.y, b = blockIdx.x;
    const int tid = threadIdx.x;
    const int bcnt = gcur[r * NBKT + b];
    const int gbase = bpre[r * NBKT + b];
    const uint2* reg = ebuf + (size_t)(r * NBKT + b) * BCAP;
    for (int i = tid; i < 512; i += 256) bins[i] = 0;
    __syncthreads();
    for (int i = tid; i < bcnt; i += 256) atomicAdd(&bins[reg[i].y & 511], 1);
    __syncthreads();
    int v0 = bins[2 * tid], v1 = bins[2 * tid + 1];
    sc[tid] = v0 + v1;
    __syncthreads();
    for (int off = 1; off < 256; off <<= 1) {
        int t = 0;
        if (tid >= off) t = sc[tid - off];
        __syncthreads();
        sc[tid] += t;
        __syncthreads();
    }
    int base = sc[tid] - (v0 + v1);            // exclusive over pairs
    bst[2 * tid] = base;
    bst[2 * tid + 1] = base + v0;
    cur[2 * tid] = base;
    cur[2 * tid + 1] = base + v0;
    __syncthreads();
    for (int nl = tid; nl < 512; nl += 256) {
        int n = (b << BKT_SH) + nl;
        if (n < N) rowptr[r * (N + 1) + n] = gbase + bst[nl];
    }
    if (b == NBKT - 1 && tid == 0) rowptr[r * (N + 1) + N] = gbase + bcnt;
    for (int i = tid; i < bcnt; i += 256) {
        uint2 e = reg[i];
        int p = atomicAdd(&cur[e.y & 511], 1);
        img[p] = e.x;
    }
    __syncthreads();
    for (int i = tid; i < bcnt; i += 256) srclist[(size_t)r * E + gbase + i] = img[i];
}

// ---------------- W prep: transpose to [col][k] and split hi/lo bf16 ----------------

__global__ __launch_bounds__(128) void prep_w(const float* __restrict__ W1,
                                              const float* __restrict__ W2,
                                              short* __restrict__ Wt1H, short* __restrict__ Wt1L,
                                              short* __restrict__ Wt2H, short* __restrict__ Wt2L) {
    int b = blockIdx.x;
    int k = threadIdx.x;
    if (b < COLS1) {
        int r = b >> 7, col = b & 127;
        float v = W1[(size_t)r * 128 * 128 + (size_t)k * 128 + col];
        unsigned short h = f2bf(v);
        Wt1H[(size_t)b * K + k] = (short)h;
        Wt1L[(size_t)b * K + k] = (short)f2bf(v - bf2f(h));
    } else {
        int b2 = b - COLS1;
        int r = b2 >> 6, col = b2 & 63;
        float v = W2[(size_t)r * 128 * 64 + (size_t)k * 64 + col];
        unsigned short h = f2bf(v);
        Wt2H[(size_t)b2 * K + k] = (short)h;
        Wt2L[(size_t)b2 * K + k] = (short)f2bf(v - bf2f(h));
    }
}

// ---------------- MFMA GEMM1 + fused attn logits (layer 1) ----------------
// C/D layout (verified m89 + prior rounds): col = lane&15, row = (lane>>4)*4 + i

__device__ inline void split_a(const float* __restrict__ xrow, bf16x8* ah, bf16x8* al) {
#pragma unroll
    for (int ks = 0; ks < 4; ks++) {
        f32x4 xa = *(const f32x4*)(xrow + ks * 32);
        f32x4 xb = *(const f32x4*)(xrow + ks * 32 + 4);
#pragma unroll
        for (int i = 0; i < 4; i++) {
            unsigned short h = f2bf(xa[i]);
            ah[ks][i] = (short)h;
            al[ks][i] = (short)f2bf(xa[i] - bf2f(h));
            unsigned short h2 = f2bf(xb[i]);
            ah[ks][4 + i] = (short)h2;
            al[ks][4 + i] = (short)f2bf(xb[i] - bf2f(h2));
        }
    }
}

__global__ __launch_bounds__(256) void gemm1_mfma(const float* __restrict__ X,
                                                  const short* __restrict__ WtH,
                                                  const short* __restrict__ WtL,
                                                  const float* __restrict__ al1,
                                                  const float* __restrict__ ar1,
                                                  unsigned* __restrict__ packed1,
                                                  float* __restrict__ el,
                                                  float* __restrict__ er) {
    int wid = (blockIdx.x * 256 + threadIdx.x) >> 6;
    if (wid >= NT16) return;
    const int lane = threadIdx.x & 63;
    const int c = lane & 15;
    const int g = lane >> 4;
    const int n0 = wid * 16;
    bf16x8 ah[4], al[4];
    split_a(X + (size_t)(n0 + c) * K + g * 8, ah, al);
    for (int r = 0; r < R; r++) {
        float pel0[4] = {0.f, 0.f, 0.f, 0.f}, per0[4] = {0.f, 0.f, 0.f, 0.f};
        float pel1[4] = {0.f, 0.f, 0.f, 0.f}, per1[4] = {0.f, 0.f, 0.f, 0.f};
        for (int tr = 0; tr < 4; tr++) {
            const short* bh = WtH + (size_t)(r * 128 + tr * 16 + c) * K + g * 8;
            const short* bl = WtL + (size_t)(r * 128 + tr * 16 + c) * K + g * 8;
            f32x4 acc0 = {0.f, 0.f, 0.f, 0.f};
            f32x4 acc1 = {0.f, 0.f, 0.f, 0.f};
#pragma unroll
            for (int ks = 0; ks < 4; ks++) {
                bf16x8 b0h = *(const bf16x8*)(bh + ks * 32);
                bf16x8 b0l = *(const bf16x8*)(bl + ks * 32);
                bf16x8 b1h = *(const bf16x8*)(bh + 64 * K + ks * 32);
                bf16x8 b1l = *(const bf16x8*)(bl + 64 * K + ks * 32);
                acc0 = __builtin_amdgcn_mfma_f32_16x16x32_bf16(ah[ks], b0h, acc0, 0, 0, 0);
                acc0 = __builtin_amdgcn_mfma_f32_16x16x32_bf16(al[ks], b0h, acc0, 0, 0, 0);
                acc0 = __builtin_amdgcn_mfma_f32_16x16x32_bf16(ah[ks], b0l, acc0, 0, 0, 0);
                acc1 = __builtin_amdgcn_mfma_f32_16x16x32_bf16(ah[ks], b1h, acc1, 0, 0, 0);
                acc1 = __builtin_amdgcn_mfma_f32_16x16x32_bf16(al[ks], b1h, acc1, 0, 0, 0);
                acc1 = __builtin_amdgcn_mfma_f32_16x16x32_bf16(ah[ks], b1l, acc1, 0, 0, 0);
            }
            float a0 = al1[r * 128 + tr * 16 + c];
            float r0 = ar1[r * 128 + tr * 16 + c];
            float a1 = al1[r * 128 + 64 + tr * 16 + c];
            float r1 = ar1[r * 128 + 64 + tr * 16 + c];
#pragma unroll
            for (int i = 0; i < 4; i++) {
                pel0[i] += acc0[i] * a0;
                per0[i] += acc0[i] * r0;
                pel1[i] += acc1[i] * a1;
                per1[i] += acc1[i] * r1;
                int m = g * 4 + i;
                unsigned wrd = (unsigned)f2bf(acc0[i]) | ((unsigned)f2bf(acc1[i]) << 16);
                packed1[(size_t)(n0 + m) * 192 + r * 64 + tr * 16 + c] = wrd;
            }
        }
        // reduce logits across the 16 c-lanes (same g)
#pragma unroll
        for (int off = 1; off < 16; off <<= 1) {
#pragma unroll
            for (int i = 0; i < 4; i++) {
                pel0[i] += __shfl_xor(pel0[i], off);
                per0[i] += __shfl_xor(per0[i], off);
                pel1[i] += __shfl_xor(pel1[i], off);
                per1[i] += __shfl_xor(per1[i], off);
            }
        }
        if (c == 0) {
#pragma unroll
            for (int i = 0; i < 4; i++) {
                int n = n0 + g * 4 + i;
                el[(r * N + n) * 2 + 0] = pel0[i];
                el[(r * N + n) * 2 + 1] = pel1[i];
                er[(r * N + n) * 2 + 0] = per0[i];
                er[(r * N + n) * 2 + 1] = per1[i];
            }
        }
    }
}

// ---------------- MFMA GEMM2 + fused attn logits (layer 2) ----------------

__global__ __launch_bounds__(256) void gemm2_mfma(const float* __restrict__ X,
                                                  const short* __restrict__ WtH,
                                                  const short* __restrict__ WtL,
                                                  const float* __restrict__ al2,
                                                  const float* __restrict__ ar2,
                                                  unsigned short* __restrict__ packed2,
                                                  float* __restrict__ el,
                                                  float* __restrict__ er) {
    int wid = (blockIdx.x * 256 + threadIdx.x) >> 6;
    if (wid >= NT16) return;
    const int lane = threadIdx.x & 63;
    const int c = lane & 15;
    const int g = lane >> 4;
    const int n0 = wid * 16;
    bf16x8 ah[4], al[4];
    split_a(X + (size_t)(n0 + c) * K + g * 8, ah, al);
    float pel[4], per[4];
    for (int t = 0; t < 12; t++) {
        int r = t >> 2, tt = t & 3;
        if (tt == 0) {
#pragma unroll
            for (int i = 0; i < 4; i++) { pel[i] = 0.f; per[i] = 0.f; }
        }
        const short* bh = WtH + (size_t)(t * 16 + c) * K + g * 8;
        const short* bl = WtL + (size_t)(t * 16 + c) * K + g * 8;
        f32x4 acc = {0.f, 0.f, 0.f, 0.f};
#pragma unroll
        for (int ks = 0; ks < 4; ks++) {
            bf16x8 vh = *(const bf16x8*)(bh + ks * 32);
            bf16x8 vl = *(const bf16x8*)(bl + ks * 32);
            acc = __builtin_amdgcn_mfma_f32_16x16x32_bf16(ah[ks], vh, acc, 0, 0, 0);
            acc = __builtin_amdgcn_mfma_f32_16x16x32_bf16(al[ks], vh, acc, 0, 0, 0);
            acc = __builtin_amdgcn_mfma_f32_16x16x32_bf16(ah[ks], vl, acc, 0, 0, 0);
        }
        float a = al2[r * 64 + tt * 16 + c];
        float rr = ar2[r * 64 + tt * 16 + c];
#pragma unroll
        for (int i = 0; i < 4; i++) {
            pel[i] += acc[i] * a;
            per[i] += acc[i] * rr;
            int m = g * 4 + i;
            packed2[(size_t)(n0 + m) * 192 + t * 16 + c] = f2bf(acc[i]);
        }
        if (tt == 3) {
#pragma unroll
            for (int off = 1; off < 16; off <<= 1) {
#pragma unroll
                for (int i = 0; i < 4; i++) {
                    pel[i] += __shfl_xor(pel[i], off);
                    per[i] += __shfl_xor(per[i], off);
                }
            }
            if (c == 0) {
#pragma unroll
                for (int i = 0; i < 4; i++) {
                    int n = n0 + g * 4 + i;
                    el[r * N + n] = pel[i];
                    er[r * N + n] = per[i];
                }
            }
        }
    }
}

// ---------------- aggregation: lane-parallel edge prep + deep-unrolled gathers ----------------

__global__ void agg_l1(const unsigned* __restrict__ packed1,
                       const float* __restrict__ el_, const float* __restrict__ er_,
                       const int* __restrict__ rowptr, const int* __restrict__ srclist,
                       const float* __restrict__ b1, float* __restrict__ h1) {
    int n = (blockIdx.x * blockDim.x + threadIdx.x) >> 6;
    int lane = threadIdx.x & 63;
    if (n >= N) return;
    const float2* el2 = (const float2*)el_;
    const float2* er2 = (const float2*)er_;
    float h0 = 0.f, h1v = 0.f;
    for (int r = 0; r < R; r++) {
        int beg = rowptr[r * (N + 1) + n];
        int end = rowptr[r * (N + 1) + n + 1];
        float2 ern = er2[r * N + n];
        const int* sl = srclist + r * E;
        const int rbase = r * N;
        float acc0 = 0.f, acc1 = 0.f, zl0 = 0.f, zl1 = 0.f;
        for (int cbeg = beg; cbeg < end; cbeg += 64) {
            int cnt = min(64, end - cbeg);
            int sid = 0;
            float ew0 = 0.f, ew1 = 0.f;
            if (lane < cnt) {
                sid = sl[cbeg + lane];
                float2 e = el2[rbase + sid];
                ew0 = __expf(lrelu02(e.x + ern.x));
                ew1 = __expf(lrelu02(e.y + ern.y));
            }
            zl0 += ew0;
            zl1 += ew1;
            int k = 0;
            for (; k + 3 < cnt; k += 4) {
                int s0 = __shfl(sid, k), s1 = __shfl(sid, k + 1);
                int s2 = __shfl(sid, k + 2), s3 = __shfl(sid, k + 3);
                float a00 = __shfl(ew0, k), a01 = __shfl(ew0, k + 1);
                float a02 = __shfl(ew0, k + 2), a03 = __shfl(ew0, k + 3);
                float a10 = __shfl(ew1, k), a11 = __shfl(ew1, k + 1);
                float a12 = __shfl(ew1, k + 2), a13 = __shfl(ew1, k + 3);
                unsigned p0 = packed1[((size_t)s0 * R + r) * 64 + lane];
                unsigned p1 = packed1[((size_t)s1 * R + r) * 64 + lane];
                unsigned p2 = packed1[((size_t)s2 * R + r) * 64 + lane];
                unsigned p3 = packed1[((size_t)s3 * R + r) * 64 + lane];
                acc0 += a00 * bf2f_lo(p0) + a01 * bf2f_lo(p1);
                acc1 += a10 * bf2f_hi(p0) + a11 * bf2f_hi(p1);
                acc0 += a02 * bf2f_lo(p2) + a03 * bf2f_lo(p3);
                acc1 += a12 * bf2f_hi(p2) + a13 * bf2f_hi(p3);
            }
            for (; k < cnt; k++) {
                int s = __shfl(sid, k);
                float a0 = __shfl(ew0, k);
                float a1 = __shfl(ew1, k);
                unsigned p = packed1[((size_t)s * R + r) * 64 + lane];
                acc0 += a0 * bf2f_lo(p);
                acc1 += a1 * bf2f_hi(p);
            }
        }
#pragma unroll
        for (int off = 32; off; off >>= 1) {
            zl0 += __shfl_xor(zl0, off);
            zl1 += __shfl_xor(zl1, off);
        }
        float rz0 = (end > beg) ? 1.f / zl0 : 0.f;
        float rz1 = (end > beg) ? 1.f / zl1 : 0.f;
        h0 += elu1(acc0 * rz0 + b1[r * 128 + lane]);
        h1v += elu1(acc1 * rz1 + b1[r * 128 + 64 + lane]);
    }
    h1[(size_t)n * 128 + lane] = h0;
    h1[(size_t)n * 128 + 64 + lane] = h1v;
}

// agg layer2 fused with final linear (Wl staged in LDS)
__global__ __launch_bounds__(256) void agg_l2_final(const unsigned short* __restrict__ packed2,
                                                    const float* __restrict__ el,
                                                    const float* __restrict__ er,
                                                    const int* __restrict__ rowptr,
                                                    const int* __restrict__ srclist,
                                                    const float* __restrict__ b2,
                                                    const float* __restrict__ Wl,
                                                    const float* __restrict__ bl,
                                                    float* __restrict__ out) {
    __shared__ float wl_s[64 * 64];
    for (int t = threadIdx.x; t < 64 * 64; t += 256) wl_s[t] = Wl[t];
    __syncthreads();
    int n = (blockIdx.x * blockDim.x + threadIdx.x) >> 6;
    int lane = threadIdx.x & 63;
    if (n >= N) return;
    float hacc = 0.f;
    for (int r = 0; r < R; r++) {
        int beg = rowptr[r * (N + 1) + n];
        int end = rowptr[r * (N + 1) + n + 1];
        float ern = er[r * N + n];
        const int* sl = srclist + r * E;
        const int rbase = r * N;
        float acc = 0.f, zl = 0.f;
        for (int cbeg = beg; cbeg < end; cbeg += 64) {
            int cnt = min(64, end - cbeg);
            int sid = 0;
            float ew = 0.f;
            if (lane < cnt) {
                sid = sl[cbeg + lane];
                ew = __expf(lrelu02(el[rbase + sid] + ern));
            }
            zl += ew;
            int k = 0;
            for (; k + 3 < cnt; k += 4) {
                int s0 = __shfl(sid, k), s1 = __shfl(sid, k + 1);
                int s2 = __shfl(sid, k + 2), s3 = __shfl(sid, k + 3);
                float a0 = __shfl(ew, k), a1 = __shfl(ew, k + 1);
                float a2 = __shfl(ew, k + 2), a3 = __shfl(ew, k + 3);
                float f0 = bf2f(packed2[((size_t)s0 * R + r) * 64 + lane]);
                float f1 = bf2f(packed2[((size_t)s1 * R + r) * 64 + lane]);
                float f2 = bf2f(packed2[((size_t)s2 * R + r) * 64 + lane]);
                float f3 = bf2f(packed2[((size_t)s3 * R + r) * 64 + lane]);
                acc += a0 * f0 + a1 * f1 + a2 * f2 + a3 * f3;
            }
            for (; k < cnt; k++) {
                int s = __shfl(sid, k);
                float a = __shfl(ew, k);
                acc += a * bf2f(packed2[((size_t)s * R + r) * 64 + lane]);
            }
        }
#pragma unroll
        for (int off = 32; off; off >>= 1) zl += __shfl_xor(zl, off);
        float rz = (end > beg) ? 1.f / zl : 0.f;
        hacc += elu1(acc * rz + b2[r * 64 + lane]);
    }
    float res = bl[lane];
#pragma unroll
    for (int kk = 0; kk < 64; kk++) {
        float xk = __shfl(hacc, kk);
        res += xk * wl_s[kk * 64 + lane];
    }
    out[(size_t)n * 64 + lane] = res;
}

// ---------------- launch ----------------

extern "C" void kernel_launch(void* const* d_in, const int* in_sizes, int n_in,
                              void* d_out, int out_size, void* d_ws, size_t ws_size,
                              hipStream_t stream) {
    const float* x   = (const float*)d_in[0];
    const int*   src = (const int*)d_in[1];
    const int*   dst = (const int*)d_in[2];
    const float* W1  = (const float*)d_in[3];
    const float* al1 = (const float*)d_in[4];
    const float* ar1 = (const float*)d_in[5];
    const float* b1  = (const float*)d_in[6];
    const float* W2  = (const float*)d_in[7];
    const float* al2 = (const float*)d_in[8];
    const float* ar2 = (const float*)d_in[9];
    const float* b2  = (const float*)d_in[10];
    const float* Wl  = (const float*)d_in[11];
    const float* bl  = (const float*)d_in[12];
    float* out = (float*)d_out;

    char* ws = (char*)d_ws;
    size_t off = 0;
    auto alloc = [&](size_t bytes) {
        char* p = ws + off;
        off += (bytes + 255) & ~(size_t)255;
        return p;
    };
    unsigned*       packed1 = (unsigned*)alloc(sizeof(unsigned) * (size_t)N * R * 64);        // 38.4 MB
    unsigned short* packed2 = (unsigned short*)alloc(sizeof(unsigned short) * (size_t)N * R * 64); // 19.2 MB
    float* h1      = (float*)alloc(sizeof(float) * (size_t)N * 128);    // 25.6 MB
    float* el1     = (float*)alloc(sizeof(float) * (size_t)R * N * 2);
    float* er1     = (float*)alloc(sizeof(float) * (size_t)R * N * 2);
    float* el2     = (float*)alloc(sizeof(float) * (size_t)R * N);
    float* er2     = (float*)alloc(sizeof(float) * (size_t)R * N);
    int*   rowptr  = (int*)alloc(sizeof(int) * (size_t)R * (N + 1));
    int*   srclist = (int*)alloc(sizeof(int) * (size_t)R * E);          // 9.6 MB
    uint2* ebuf    = (uint2*)alloc(sizeof(uint2) * (size_t)R * NBKT * BCAP); // 24.1 MB
    int*   gcur    = (int*)alloc(sizeof(int) * (size_t)R * NBKT);
    int*   bpre    = (int*)alloc(sizeof(int) * (size_t)R * NBKT);
    short* Wt1H    = (short*)alloc(sizeof(short) * (size_t)COLS1 * K);
    short* Wt1L    = (short*)alloc(sizeof(short) * (size_t)COLS1 * K);
    short* Wt2H    = (short*)alloc(sizeof(short) * (size_t)COLS2 * K);
    short* Wt2L    = (short*)alloc(sizeof(short) * (size_t)COLS2 * K);

    // --- W prep + CSR build ---
    hipMemsetAsync(gcur, 0, sizeof(int) * (size_t)R * NBKT, stream);
    prep_w<<<COLS1 + COLS2, 128, 0, stream>>>(W1, W2, Wt1H, Wt1L, Wt2H, Wt2L);
    {
        dim3 g1(P1B, R);
        bucket_p1<<<g1, 256, 0, stream>>>(src, dst, gcur, ebuf);
        bucket_scan<<<1, 192, 0, stream>>>(gcur, bpre);
        dim3 g2(NBKT, R);
        bucket_p2<<<g2, 256, 0, stream>>>(ebuf, gcur, bpre, rowptr, srclist);
    }

    // --- layer 1 ---
    gemm1_mfma<<<(NT16 * 64 + 255) / 256, 256, 0, stream>>>(x, Wt1H, Wt1L, al1, ar1,
                                                            packed1, el1, er1);
    agg_l1<<<(N * 64 + 255) / 256, 256, 0, stream>>>(packed1, el1, er1, rowptr, srclist, b1, h1);

    // --- layer 2 ---
    gemm2_mfma<<<(NT16 * 64 + 255) / 256, 256, 0, stream>>>(h1, Wt2H, Wt2L, al2, ar2,
                                                            packed2, el2, er2);
    agg_l2_final<<<(N * 64 + 255) / 256, 256, 0, stream>>>(packed2, el2, er2, rowptr, srclist,
                                                           b2, Wl, bl, out);
}

// Round 7
// 389.584 us; speedup vs baseline: 2.8195x; 1.1136x over previous
//
#include <hip/hip_runtime.h>

constexpr int R = 3;
constexpr int N = 50000;
constexpr int E = 800000;
constexpr int K = 128;        // IN = HEADS*HID = 128 (both GEMM K dims)
constexpr int COLS1 = 384;    // R * HEADS * HID
constexpr int COLS2 = 192;    // R * HID
constexpr int NT16 = N / 16;  // 3125 node-tiles for MFMA GEMMs

// bucketed CSR build
constexpr int BKT_SH = 9;                    // 512 nodes per bucket
constexpr int NBKT = (N + 511) >> 9;         // 98 buckets per relation
constexpr int BCAP = 10240;                  // bucket capacity (avg 8163)
constexpr int P1E = 4096;                    // edges per pass-1 block
constexpr int P1B = (E + P1E - 1) / P1E;     // 196 blocks per relation

typedef __attribute__((ext_vector_type(8))) short bf16x8;
typedef __attribute__((ext_vector_type(4))) float f32x4;

// ---------------- bf16 helpers (RNE) ----------------

__device__ inline unsigned short f2bf(float f) {
    unsigned u = __float_as_uint(f);
    u += 0x7FFF + ((u >> 16) & 1);
    return (unsigned short)(u >> 16);
}
__device__ inline float bf2f_lo(unsigned p) { return __uint_as_float(p << 16); }
__device__ inline float bf2f_hi(unsigned p) { return __uint_as_float(p & 0xFFFF0000u); }
__device__ inline float bf2f(unsigned short b) { return __uint_as_float(((unsigned)b) << 16); }

__device__ inline float lrelu02(float x) { return x > 0.f ? x : 0.2f * x; }
__device__ inline float elu1(float x) { return x > 0.f ? x : expm1f(x); }

// ---------------- CSR build: pass 1 (bucket scatter, coalesced) ----------------

__global__ __launch_bounds__(256) void bucket_p1(const int* __restrict__ src,
                                                 const int* __restrict__ dst,
                                                 int* __restrict__ gcur,
                                                 uint2* __restrict__ ebuf) {
    __shared__ uint2 img[P1E];                 // 32 KB
    __shared__ int bins[NBKT], bstart[NBKT], gbase[NBKT];
    __shared__ int sc[128];
    const int r = blockIdx.y;
    const int e0 = blockIdx.x * P1E;
    const int cnt = min(P1E, E - e0);
    const int tid = threadIdx.x;
    if (tid < NBKT) bins[tid] = 0;
    __syncthreads();
    int sv[16], dv[16], rk[16];
    int ni = 0;
    for (int i = tid; i < cnt; i += 256, ni++) {
        sv[ni] = src[(size_t)r * E + e0 + i];
        dv[ni] = dst[(size_t)r * E + e0 + i];
        rk[ni] = atomicAdd(&bins[dv[ni] >> BKT_SH], 1);
    }
    __syncthreads();
    if (tid < 128) sc[tid] = (tid < NBKT) ? bins[tid] : 0;
    __syncthreads();
    for (int off = 1; off < 128; off <<= 1) {
        int v = 0;
        if (tid < 128 && tid >= off) v = sc[tid - off];
        __syncthreads();
        if (tid < 128) sc[tid] += v;
        __syncthreads();
    }
    if (tid < NBKT) bstart[tid] = sc[tid] - bins[tid];
    __syncthreads();
    for (int j = 0; j < ni; j++) {
        int b = dv[j] >> BKT_SH;
        img[bstart[b] + rk[j]] = make_uint2((unsigned)sv[j], (unsigned)dv[j]);
    }
    if (tid < NBKT) gbase[tid] = bins[tid] ? atomicAdd(&gcur[r * NBKT + tid], bins[tid]) : 0;
    __syncthreads();
    for (int i = tid; i < cnt; i += 256) {
        uint2 e = img[i];
        int b = (int)(e.y >> BKT_SH);
        int pos = gbase[b] + (i - bstart[b]);
        if (pos < BCAP) ebuf[(size_t)(r * NBKT + b) * BCAP + pos] = e;
    }
}

__global__ void bucket_scan(const int* __restrict__ gcur, int* __restrict__ bpre) {
    int w = threadIdx.x >> 6, lane = threadIdx.x & 63;
    if (w >= R) return;
    const int* g = gcur + w * NBKT;
    int* p = bpre + w * NBKT;
    int carry = 0;
    for (int base = 0; base < NBKT; base += 64) {
        int v = (base + lane < NBKT) ? g[base + lane] : 0;
        int x = v;
#pragma unroll
        for (int off = 1; off < 64; off <<= 1) {
            int t = __shfl_up(x, off);
            if (lane >= off) x += t;
        }
        if (base + lane < NBKT) p[base + lane] = carry + x - v;
        carry += __shfl(x, 63);
    }
}

__global__ __launch_bounds__(256) void bucket_p2(const uint2* __restrict__ ebuf,
                                                 const int* __restrict__ gcur,
                                                 const int* __restrict__ bpre,
                                                 int* __restrict__ rowptr,
                                                 int* __restrict__ srclist) {
    __shared__ unsigned img[BCAP];             // 40 KB
    __shared__ int bins[512], bst[512], cur[512], sc[256];
    const int r = blockIdx.y, b = blockIdx.x;
    const int tid = threadIdx.x;
    const int bcnt = gcur[r * NBKT + b];
    const int gbase = bpre[r * NBKT + b];
    const uint2* reg = ebuf + (size_t)(r * NBKT + b) * BCAP;
    for (int i = tid; i < 512; i += 256) bins[i] = 0;
    __syncthreads();
    for (int i = tid; i < bcnt; i += 256) atomicAdd(&bins[reg[i].y & 511], 1);
    __syncthreads();
    int v0 = bins[2 * tid], v1 = bins[2 * tid + 1];
    sc[tid] = v0 + v1;
    __syncthreads();
    for (int off = 1; off < 256; off <<= 1) {
        int t = 0;
        if (tid >= off) t = sc[tid - off];
        __syncthreads();
        sc[tid] += t;
        __syncthreads();
    }
    int base = sc[tid] - (v0 + v1);
    bst[2 * tid] = base;
    bst[2 * tid + 1] = base + v0;
    cur[2 * tid] = base;
    cur[2 * tid + 1] = base + v0;
    __syncthreads();
    for (int nl = tid; nl < 512; nl += 256) {
        int n = (b << BKT_SH) + nl;
        if (n < N) rowptr[r * (N + 1) + n] = gbase + bst[nl];
    }
    if (b == NBKT - 1 && tid == 0) rowptr[r * (N + 1) + N] = gbase + bcnt;
    for (int i = tid; i < bcnt; i += 256) {
        uint2 e = reg[i];
        int p = atomicAdd(&cur[e.y & 511], 1);
        img[p] = e.x;
    }
    __syncthreads();
    for (int i = tid; i < bcnt; i += 256) srclist[(size_t)r * E + gbase + i] = img[i];
}

// ---------------- W prep: transpose to [col][k] and split hi/lo bf16 ----------------

__global__ __launch_bounds__(128) void prep_w(const float* __restrict__ W1,
                                              const float* __restrict__ W2,
                                              const float* __restrict__ Wl,
                                              short* __restrict__ Wt1H, short* __restrict__ Wt1L,
                                              short* __restrict__ Wt2H, short* __restrict__ Wt2L,
                                              short* __restrict__ Wt3H, short* __restrict__ Wt3L) {
    int b = blockIdx.x;
    int k = threadIdx.x;
    if (b < COLS1) {
        int r = b >> 7, col = b & 127;
        float v = W1[(size_t)r * 128 * 128 + (size_t)k * 128 + col];
        unsigned short h = f2bf(v);
        Wt1H[(size_t)b * K + k] = (short)h;
        Wt1L[(size_t)b * K + k] = (short)f2bf(v - bf2f(h));
    } else if (b < COLS1 + COLS2) {
        int b2 = b - COLS1;
        int r = b2 >> 6, col = b2 & 63;
        float v = W2[(size_t)r * 128 * 64 + (size_t)k * 64 + col];
        unsigned short h = f2bf(v);
        Wt2H[(size_t)b2 * K + k] = (short)h;
        Wt2L[(size_t)b2 * K + k] = (short)f2bf(v - bf2f(h));
    } else if (k < 64) {
        int col = b - COLS1 - COLS2;
        float v = Wl[(size_t)k * 64 + col];
        unsigned short h = f2bf(v);
        Wt3H[(size_t)col * 64 + k] = (short)h;
        Wt3L[(size_t)col * 64 + k] = (short)f2bf(v - bf2f(h));
    }
}

// ---------------- MFMA GEMM1 + fused attn logits (layer 1) ----------------
// C/D layout: col = lane&15, row = (lane>>4)*4 + i

__device__ inline void split_a(const float* __restrict__ xrow, bf16x8* ah, bf16x8* al) {
#pragma unroll
    for (int ks = 0; ks < 4; ks++) {
        f32x4 xa = *(const f32x4*)(xrow + ks * 32);
        f32x4 xb = *(const f32x4*)(xrow + ks * 32 + 4);
#pragma unroll
        for (int i = 0; i < 4; i++) {
            unsigned short h = f2bf(xa[i]);
            ah[ks][i] = (short)h;
            al[ks][i] = (short)f2bf(xa[i] - bf2f(h));
            unsigned short h2 = f2bf(xb[i]);
            ah[ks][4 + i] = (short)h2;
            al[ks][4 + i] = (short)f2bf(xb[i] - bf2f(h2));
        }
    }
}

__global__ __launch_bounds__(256) void gemm1_mfma(const float* __restrict__ X,
                                                  const short* __restrict__ WtH,
                                                  const short* __restrict__ WtL,
                                                  const float* __restrict__ al1,
                                                  const float* __restrict__ ar1,
                                                  unsigned* __restrict__ packed1,
                                                  float* __restrict__ el,
                                                  float* __restrict__ er) {
    int wid = (blockIdx.x * 256 + threadIdx.x) >> 6;
    if (wid >= NT16) return;
    const int lane = threadIdx.x & 63;
    const int c = lane & 15;
    const int g = lane >> 4;
    const int n0 = wid * 16;
    bf16x8 ah[4], al[4];
    split_a(X + (size_t)(n0 + c) * K + g * 8, ah, al);
    for (int r = 0; r < R; r++) {
        float pel0[4] = {0.f, 0.f, 0.f, 0.f}, per0[4] = {0.f, 0.f, 0.f, 0.f};
        float pel1[4] = {0.f, 0.f, 0.f, 0.f}, per1[4] = {0.f, 0.f, 0.f, 0.f};
        for (int tr = 0; tr < 4; tr++) {
            const short* bh = WtH + (size_t)(r * 128 + tr * 16 + c) * K + g * 8;
            const short* bl = WtL + (size_t)(r * 128 + tr * 16 + c) * K + g * 8;
            f32x4 acc0 = {0.f, 0.f, 0.f, 0.f};
            f32x4 acc1 = {0.f, 0.f, 0.f, 0.f};
#pragma unroll
            for (int ks = 0; ks < 4; ks++) {
                bf16x8 b0h = *(const bf16x8*)(bh + ks * 32);
                bf16x8 b0l = *(const bf16x8*)(bl + ks * 32);
                bf16x8 b1h = *(const bf16x8*)(bh + 64 * K + ks * 32);
                bf16x8 b1l = *(const bf16x8*)(bl + 64 * K + ks * 32);
                acc0 = __builtin_amdgcn_mfma_f32_16x16x32_bf16(ah[ks], b0h, acc0, 0, 0, 0);
                acc0 = __builtin_amdgcn_mfma_f32_16x16x32_bf16(al[ks], b0h, acc0, 0, 0, 0);
                acc0 = __builtin_amdgcn_mfma_f32_16x16x32_bf16(ah[ks], b0l, acc0, 0, 0, 0);
                acc1 = __builtin_amdgcn_mfma_f32_16x16x32_bf16(ah[ks], b1h, acc1, 0, 0, 0);
                acc1 = __builtin_amdgcn_mfma_f32_16x16x32_bf16(al[ks], b1h, acc1, 0, 0, 0);
                acc1 = __builtin_amdgcn_mfma_f32_16x16x32_bf16(ah[ks], b1l, acc1, 0, 0, 0);
            }
            float a0 = al1[r * 128 + tr * 16 + c];
            float r0 = ar1[r * 128 + tr * 16 + c];
            float a1 = al1[r * 128 + 64 + tr * 16 + c];
            float r1 = ar1[r * 128 + 64 + tr * 16 + c];
#pragma unroll
            for (int i = 0; i < 4; i++) {
                pel0[i] += acc0[i] * a0;
                per0[i] += acc0[i] * r0;
                pel1[i] += acc1[i] * a1;
                per1[i] += acc1[i] * r1;
                int m = g * 4 + i;
                unsigned wrd = (unsigned)f2bf(acc0[i]) | ((unsigned)f2bf(acc1[i]) << 16);
                packed1[(size_t)(n0 + m) * 192 + r * 64 + tr * 16 + c] = wrd;
            }
        }
#pragma unroll
        for (int off = 1; off < 16; off <<= 1) {
#pragma unroll
            for (int i = 0; i < 4; i++) {
                pel0[i] += __shfl_xor(pel0[i], off);
                per0[i] += __shfl_xor(per0[i], off);
                pel1[i] += __shfl_xor(pel1[i], off);
                per1[i] += __shfl_xor(per1[i], off);
            }
        }
        if (c == 0) {
#pragma unroll
            for (int i = 0; i < 4; i++) {
                int n = n0 + g * 4 + i;
                el[(r * N + n) * 2 + 0] = pel0[i];
                el[(r * N + n) * 2 + 1] = pel1[i];
                er[(r * N + n) * 2 + 0] = per0[i];
                er[(r * N + n) * 2 + 1] = per1[i];
            }
        }
    }
}

// ---------------- MFMA GEMM2 + fused attn logits (layer 2) ----------------

__global__ __launch_bounds__(256) void gemm2_mfma(const float* __restrict__ X,
                                                  const short* __restrict__ WtH,
                                                  const short* __restrict__ WtL,
                                                  const float* __restrict__ al2,
                                                  const float* __restrict__ ar2,
                                                  unsigned short* __restrict__ packed2,
                                                  float* __restrict__ el,
                                                  float* __restrict__ er) {
    int wid = (blockIdx.x * 256 + threadIdx.x) >> 6;
    if (wid >= NT16) return;
    const int lane = threadIdx.x & 63;
    const int c = lane & 15;
    const int g = lane >> 4;
    const int n0 = wid * 16;
    bf16x8 ah[4], al[4];
    split_a(X + (size_t)(n0 + c) * K + g * 8, ah, al);
    float pel[4], per[4];
    for (int t = 0; t < 12; t++) {
        int r = t >> 2, tt = t & 3;
        if (tt == 0) {
#pragma unroll
            for (int i = 0; i < 4; i++) { pel[i] = 0.f; per[i] = 0.f; }
        }
        const short* bh = WtH + (size_t)(t * 16 + c) * K + g * 8;
        const short* bl = WtL + (size_t)(t * 16 + c) * K + g * 8;
        f32x4 acc = {0.f, 0.f, 0.f, 0.f};
#pragma unroll
        for (int ks = 0; ks < 4; ks++) {
            bf16x8 vh = *(const bf16x8*)(bh + ks * 32);
            bf16x8 vl = *(const bf16x8*)(bl + ks * 32);
            acc = __builtin_amdgcn_mfma_f32_16x16x32_bf16(ah[ks], vh, acc, 0, 0, 0);
            acc = __builtin_amdgcn_mfma_f32_16x16x32_bf16(al[ks], vh, acc, 0, 0, 0);
            acc = __builtin_amdgcn_mfma_f32_16x16x32_bf16(ah[ks], vl, acc, 0, 0, 0);
        }
        float a = al2[r * 64 + tt * 16 + c];
        float rr = ar2[r * 64 + tt * 16 + c];
#pragma unroll
        for (int i = 0; i < 4; i++) {
            pel[i] += acc[i] * a;
            per[i] += acc[i] * rr;
            int m = g * 4 + i;
            packed2[(size_t)(n0 + m) * 192 + t * 16 + c] = f2bf(acc[i]);
        }
        if (tt == 3) {
#pragma unroll
            for (int off = 1; off < 16; off <<= 1) {
#pragma unroll
                for (int i = 0; i < 4; i++) {
                    pel[i] += __shfl_xor(pel[i], off);
                    per[i] += __shfl_xor(per[i], off);
                }
            }
            if (c == 0) {
#pragma unroll
                for (int i = 0; i < 4; i++) {
                    int n = n0 + g * 4 + i;
                    el[r * N + n] = pel[i];
                    er[r * N + n] = per[i];
                }
            }
        }
    }
}

// ---------------- aggregation: 4 edges per gather instruction ----------------
// wave = 1 node; q = lane>>4 picks edge within a 4-edge group, c = lane&15 picks dim quad

__global__ void agg_l1(const unsigned* __restrict__ packed1,
                       const float* __restrict__ el_, const float* __restrict__ er_,
                       const int* __restrict__ rowptr, const int* __restrict__ srclist,
                       const float* __restrict__ b1, float* __restrict__ h1) {
    int n = (blockIdx.x * blockDim.x + threadIdx.x) >> 6;
    int lane = threadIdx.x & 63;
    if (n >= N) return;
    const int q = lane >> 4;
    const int c = lane & 15;
    const float2* el2 = (const float2*)el_;
    const float2* er2 = (const float2*)er_;
    float hacc0[4] = {0.f, 0.f, 0.f, 0.f}, hacc1[4] = {0.f, 0.f, 0.f, 0.f};
    for (int r = 0; r < R; r++) {
        int beg = rowptr[r * (N + 1) + n];
        int end = rowptr[r * (N + 1) + n + 1];
        float2 ern = er2[r * N + n];
        const int* sl = srclist + r * E;
        const int rbase = r * N;
        float acc0[4] = {0.f, 0.f, 0.f, 0.f}, acc1[4] = {0.f, 0.f, 0.f, 0.f};
        float zl0 = 0.f, zl1 = 0.f;
        for (int cbeg = beg; cbeg < end; cbeg += 64) {
            int cnt = min(64, end - cbeg);
            int sid = 0;
            float ew0 = 0.f, ew1 = 0.f;
            if (lane < cnt) {
                sid = sl[cbeg + lane];
                float2 e = el2[rbase + sid];
                ew0 = __expf(lrelu02(e.x + ern.x));
                ew1 = __expf(lrelu02(e.y + ern.y));
            }
            zl0 += ew0;
            zl1 += ew1;
            int kmax = (cnt + 3) & ~3;
            int k = 0;
            for (; k + 8 <= kmax; k += 8) {
                int idxA = k + q, idxB = k + 4 + q;
                int sA = __shfl(sid, idxA), sB = __shfl(sid, idxB);
                float a0A = __shfl(ew0, idxA), a1A = __shfl(ew1, idxA);
                float a0B = __shfl(ew0, idxB), a1B = __shfl(ew1, idxB);
                uint4 vA = *(const uint4*)(packed1 + (size_t)sA * 192 + r * 64 + c * 4);
                uint4 vB = *(const uint4*)(packed1 + (size_t)sB * 192 + r * 64 + c * 4);
                acc0[0] += a0A * bf2f_lo(vA.x); acc1[0] += a1A * bf2f_hi(vA.x);
                acc0[1] += a0A * bf2f_lo(vA.y); acc1[1] += a1A * bf2f_hi(vA.y);
                acc0[2] += a0A * bf2f_lo(vA.z); acc1[2] += a1A * bf2f_hi(vA.z);
                acc0[3] += a0A * bf2f_lo(vA.w); acc1[3] += a1A * bf2f_hi(vA.w);
                acc0[0] += a0B * bf2f_lo(vB.x); acc1[0] += a1B * bf2f_hi(vB.x);
                acc0[1] += a0B * bf2f_lo(vB.y); acc1[1] += a1B * bf2f_hi(vB.y);
                acc0[2] += a0B * bf2f_lo(vB.z); acc1[2] += a1B * bf2f_hi(vB.z);
                acc0[3] += a0B * bf2f_lo(vB.w); acc1[3] += a1B * bf2f_hi(vB.w);
            }
            if (k < kmax) {
                int idx = k + q;
                int s = __shfl(sid, idx);
                float a0 = __shfl(ew0, idx), a1 = __shfl(ew1, idx);
                uint4 v = *(const uint4*)(packed1 + (size_t)s * 192 + r * 64 + c * 4);
                acc0[0] += a0 * bf2f_lo(v.x); acc1[0] += a1 * bf2f_hi(v.x);
                acc0[1] += a0 * bf2f_lo(v.y); acc1[1] += a1 * bf2f_hi(v.y);
                acc0[2] += a0 * bf2f_lo(v.z); acc1[2] += a1 * bf2f_hi(v.z);
                acc0[3] += a0 * bf2f_lo(v.w); acc1[3] += a1 * bf2f_hi(v.w);
            }
        }
#pragma unroll
        for (int i = 0; i < 4; i++) {
            acc0[i] += __shfl_xor(acc0[i], 16);
            acc0[i] += __shfl_xor(acc0[i], 32);
            acc1[i] += __shfl_xor(acc1[i], 16);
            acc1[i] += __shfl_xor(acc1[i], 32);
        }
#pragma unroll
        for (int off = 32; off; off >>= 1) {
            zl0 += __shfl_xor(zl0, off);
            zl1 += __shfl_xor(zl1, off);
        }
        float rz0 = (end > beg) ? 1.f / zl0 : 0.f;
        float rz1 = (end > beg) ? 1.f / zl1 : 0.f;
        float4 bv0 = *(const float4*)(b1 + r * 128 + c * 4);
        float4 bv1 = *(const float4*)(b1 + r * 128 + 64 + c * 4);
        hacc0[0] += elu1(acc0[0] * rz0 + bv0.x);
        hacc0[1] += elu1(acc0[1] * rz0 + bv0.y);
        hacc0[2] += elu1(acc0[2] * rz0 + bv0.z);
        hacc0[3] += elu1(acc0[3] * rz0 + bv0.w);
        hacc1[0] += elu1(acc1[0] * rz1 + bv1.x);
        hacc1[1] += elu1(acc1[1] * rz1 + bv1.y);
        hacc1[2] += elu1(acc1[2] * rz1 + bv1.z);
        hacc1[3] += elu1(acc1[3] * rz1 + bv1.w);
    }
    if (q == 0) {
        float4 o0 = {hacc0[0], hacc0[1], hacc0[2], hacc0[3]};
        float4 o1 = {hacc1[0], hacc1[1], hacc1[2], hacc1[3]};
        *(float4*)(h1 + (size_t)n * 128 + c * 4) = o0;
        *(float4*)(h1 + (size_t)n * 128 + 64 + c * 4) = o1;
    }
}

__global__ void agg_l2(const unsigned short* __restrict__ packed2,
                       const float* __restrict__ el, const float* __restrict__ er,
                       const int* __restrict__ rowptr, const int* __restrict__ srclist,
                       const float* __restrict__ b2, float* __restrict__ h2) {
    int n = (blockIdx.x * blockDim.x + threadIdx.x) >> 6;
    int lane = threadIdx.x & 63;
    if (n >= N) return;
    const int q = lane >> 4;
    const int c = lane & 15;
    float hacc[4] = {0.f, 0.f, 0.f, 0.f};
    for (int r = 0; r < R; r++) {
        int beg = rowptr[r * (N + 1) + n];
        int end = rowptr[r * (N + 1) + n + 1];
        float ern = er[r * N + n];
        const int* sl = srclist + r * E;
        const int rbase = r * N;
        const unsigned short* pbase = packed2 + r * 64;
        float acc[4] = {0.f, 0.f, 0.f, 0.f};
        float zl = 0.f;
        for (int cbeg = beg; cbeg < end; cbeg += 64) {
            int cnt = min(64, end - cbeg);
            int sid = 0;
            float ew = 0.f;
            if (lane < cnt) {
                sid = sl[cbeg + lane];
                ew = __expf(lrelu02(el[rbase + sid] + ern));
            }
            zl += ew;
            int kmax = (cnt + 3) & ~3;
            int k = 0;
            for (; k + 8 <= kmax; k += 8) {
                int idxA = k + q, idxB = k + 4 + q;
                int sA = __shfl(sid, idxA), sB = __shfl(sid, idxB);
                float aA = __shfl(ew, idxA), aB = __shfl(ew, idxB);
                uint2 vA = *(const uint2*)(pbase + (size_t)sA * 192 + c * 4);
                uint2 vB = *(const uint2*)(pbase + (size_t)sB * 192 + c * 4);
                acc[0] += aA * bf2f_lo(vA.x); acc[1] += aA * bf2f_hi(vA.x);
                acc[2] += aA * bf2f_lo(vA.y); acc[3] += aA * bf2f_hi(vA.y);
                acc[0] += aB * bf2f_lo(vB.x); acc[1] += aB * bf2f_hi(vB.x);
                acc[2] += aB * bf2f_lo(vB.y); acc[3] += aB * bf2f_hi(vB.y);
            }
            if (k < kmax) {
                int idx = k + q;
                int s = __shfl(sid, idx);
                float a = __shfl(ew, idx);
                uint2 v = *(const uint2*)(pbase + (size_t)s * 192 + c * 4);
                acc[0] += a * bf2f_lo(v.x); acc[1] += a * bf2f_hi(v.x);
                acc[2] += a * bf2f_lo(v.y); acc[3] += a * bf2f_hi(v.y);
            }
        }
#pragma unroll
        for (int i = 0; i < 4; i++) {
            acc[i] += __shfl_xor(acc[i], 16);
            acc[i] += __shfl_xor(acc[i], 32);
        }
#pragma unroll
        for (int off = 32; off; off >>= 1) zl += __shfl_xor(zl, off);
        float rz = (end > beg) ? 1.f / zl : 0.f;
        float4 bv = *(const float4*)(b2 + r * 64 + c * 4);
        hacc[0] += elu1(acc[0] * rz + bv.x);
        hacc[1] += elu1(acc[1] * rz + bv.y);
        hacc[2] += elu1(acc[2] * rz + bv.z);
        hacc[3] += elu1(acc[3] * rz + bv.w);
    }
    if (q == 0) {
        float4 o = {hacc[0], hacc[1], hacc[2], hacc[3]};
        *(float4*)(h2 + (size_t)n * 64 + c * 4) = o;
    }
}

// ---------------- MFMA GEMM3: out = h2[N,64] @ Wl[64,64] + bl ----------------

__global__ __launch_bounds__(256) void gemm3_mfma(const float* __restrict__ h2,
                                                  const short* __restrict__ WtH,
                                                  const short* __restrict__ WtL,
                                                  const float* __restrict__ bl,
                                                  float* __restrict__ out) {
    int wid = (blockIdx.x * 256 + threadIdx.x) >> 6;
    if (wid >= NT16) return;
    const int lane = threadIdx.x & 63;
    const int c = lane & 15;
    const int g = lane >> 4;
    const int n0 = wid * 16;
    bf16x8 ah[2], al[2];
    const float* xrow = h2 + (size_t)(n0 + c) * 64 + g * 8;
#pragma unroll
    for (int ks = 0; ks < 2; ks++) {
        f32x4 xa = *(const f32x4*)(xrow + ks * 32);
        f32x4 xb = *(const f32x4*)(xrow + ks * 32 + 4);
#pragma unroll
        for (int i = 0; i < 4; i++) {
            unsigned short h = f2bf(xa[i]);
            ah[ks][i] = (short)h;
            al[ks][i] = (short)f2bf(xa[i] - bf2f(h));
            unsigned short h2v = f2bf(xb[i]);
            ah[ks][4 + i] = (short)h2v;
            al[ks][4 + i] = (short)f2bf(xb[i] - bf2f(h2v));
        }
    }
    for (int t = 0; t < 4; t++) {
        const short* bh = WtH + (size_t)(t * 16 + c) * 64 + g * 8;
        const short* blp = WtL + (size_t)(t * 16 + c) * 64 + g * 8;
        f32x4 acc = {0.f, 0.f, 0.f, 0.f};
#pragma unroll
        for (int ks = 0; ks < 2; ks++) {
            bf16x8 vh = *(const bf16x8*)(bh + ks * 32);
            bf16x8 vl = *(const bf16x8*)(blp + ks * 32);
            acc = __builtin_amdgcn_mfma_f32_16x16x32_bf16(ah[ks], vh, acc, 0, 0, 0);
            acc = __builtin_amdgcn_mfma_f32_16x16x32_bf16(al[ks], vh, acc, 0, 0, 0);
            acc = __builtin_amdgcn_mfma_f32_16x16x32_bf16(ah[ks], vl, acc, 0, 0, 0);
        }
        float bb = bl[t * 16 + c];
#pragma unroll
        for (int i = 0; i < 4; i++) {
            out[(size_t)(n0 + g * 4 + i) * 64 + t * 16 + c] = acc[i] + bb;
        }
    }
}

// ---------------- launch ----------------

extern "C" void kernel_launch(void* const* d_in, const int* in_sizes, int n_in,
                              void* d_out, int out_size, void* d_ws, size_t ws_size,
                              hipStream_t stream) {
    const float* x   = (const float*)d_in[0];
    const int*   src = (const int*)d_in[1];
    const int*   dst = (const int*)d_in[2];
    const float* W1  = (const float*)d_in[3];
    const float* al1 = (const float*)d_in[4];
    const float* ar1 = (const float*)d_in[5];
    const float* b1  = (const float*)d_in[6];
    const float* W2  = (const float*)d_in[7];
    const float* al2 = (const float*)d_in[8];
    const float* ar2 = (const float*)d_in[9];
    const float* b2  = (const float*)d_in[10];
    const float* Wl  = (const float*)d_in[11];
    const float* bl  = (const float*)d_in[12];
    float* out = (float*)d_out;

    char* ws = (char*)d_ws;
    size_t off = 0;
    auto alloc = [&](size_t bytes) {
        char* p = ws + off;
        off += (bytes + 255) & ~(size_t)255;
        return p;
    };
    unsigned*       packed1 = (unsigned*)alloc(sizeof(unsigned) * (size_t)N * R * 64);
    unsigned short* packed2 = (unsigned short*)alloc(sizeof(unsigned short) * (size_t)N * R * 64);
    float* h1      = (float*)alloc(sizeof(float) * (size_t)N * 128);
    float* h2      = (float*)alloc(sizeof(float) * (size_t)N * 64);
    float* el1     = (float*)alloc(sizeof(float) * (size_t)R * N * 2);
    float* er1     = (float*)alloc(sizeof(float) * (size_t)R * N * 2);
    float* el2     = (float*)alloc(sizeof(float) * (size_t)R * N);
    float* er2     = (float*)alloc(sizeof(float) * (size_t)R * N);
    int*   rowptr  = (int*)alloc(sizeof(int) * (size_t)R * (N + 1));
    int*   srclist = (int*)alloc(sizeof(int) * (size_t)R * E);
    uint2* ebuf    = (uint2*)alloc(sizeof(uint2) * (size_t)R * NBKT * BCAP);
    int*   gcur    = (int*)alloc(sizeof(int) * (size_t)R * NBKT);
    int*   bpre    = (int*)alloc(sizeof(int) * (size_t)R * NBKT);
    short* Wt1H    = (short*)alloc(sizeof(short) * (size_t)COLS1 * K);
    short* Wt1L    = (short*)alloc(sizeof(short) * (size_t)COLS1 * K);
    short* Wt2H    = (short*)alloc(sizeof(short) * (size_t)COLS2 * K);
    short* Wt2L    = (short*)alloc(sizeof(short) * (size_t)COLS2 * K);
    short* Wt3H    = (short*)alloc(sizeof(short) * (size_t)64 * 64);
    short* Wt3L    = (short*)alloc(sizeof(short) * (size_t)64 * 64);

    // --- W prep + CSR build ---
    hipMemsetAsync(gcur, 0, sizeof(int) * (size_t)R * NBKT, stream);
    prep_w<<<COLS1 + COLS2 + 64, 128, 0, stream>>>(W1, W2, Wl, Wt1H, Wt1L, Wt2H, Wt2L, Wt3H, Wt3L);
    {
        dim3 g1(P1B, R);
        bucket_p1<<<g1, 256, 0, stream>>>(src, dst, gcur, ebuf);
        bucket_scan<<<1, 192, 0, stream>>>(gcur, bpre);
        dim3 g2(NBKT, R);
        bucket_p2<<<g2, 256, 0, stream>>>(ebuf, gcur, bpre, rowptr, srclist);
    }

    // --- layer 1 ---
    gemm1_mfma<<<(NT16 * 64 + 255) / 256, 256, 0, stream>>>(x, Wt1H, Wt1L, al1, ar1,
                                                            packed1, el1, er1);
    agg_l1<<<(N * 64 + 255) / 256, 256, 0, stream>>>(packed1, el1, er1, rowptr, srclist, b1, h1);

    // --- layer 2 ---
    gemm2_mfma<<<(NT16 * 64 + 255) / 256, 256, 0, stream>>>(h1, Wt2H, Wt2L, al2, ar2,
                                                            packed2, el2, er2);
    agg_l2<<<(N * 64 + 255) / 256, 256, 0, stream>>>(packed2, el2, er2, rowptr, srclist, b2, h2);

    // --- final linear (MFMA) ---
    gemm3_mfma<<<(NT16 * 64 + 255) / 256, 256, 0, stream>>>(h2, Wt3H, Wt3L, bl, out);
}